// Round 17
// baseline (141.769 us; speedup 1.0000x reference)
//
#include <hip/hip_runtime.h>

#define SEQ 6
#define THREADS 256              // 4 waves; 10 elements per wave (60 active lanes)
#define ELB 40                   // elements per block
#define NL 2
#define VOC 15
#define STR 20                   // slot stride in u32 (80B): rows span both 16-bank halves

typedef __attribute__((ext_vector_type(8))) _Float16 h8;
typedef __attribute__((ext_vector_type(2))) _Float16 h2;
typedef __attribute__((ext_vector_type(4))) float    f32x4;

// LDS: 2 pools x 256 slots x STR u32. 10240 u32 = 40 KB (3 blocks = 120KB/CU ok).
// Bank plan: stride 20 => row r starts at bank (20r)%32, consecutive rows are
// offset 16 banks => tile-writes (64 lanes, 4 rows) span all 32 banks (2-way, free).
// Group rotation k(row)=((row>>1)+(row>>3))&3 XOR'd into the 16B-group index keeps
// own-slot uint4 ops (tid/tid+8 alias at stride 20) and A-frag reads at <=2-way.
#define XN 0          // Xn -> Q -> V -> OWo -> H -> FFN2
#define KP 5120       // K -> O -> Xn2 -> logits f32
#define SMEM_U32 10240

// ws layout (u32): per layer L at L*6144: Wq 0, Wk 512, Wv 1024, Wo 1536,
// quarter q: 2048+q*1024 (W1q at +0, W2q at +512). TE at 12288 (256).

__device__ __forceinline__ unsigned int pkh(float a, float b) {
    auto h = __builtin_amdgcn_cvt_pkrtz(a, b);
    return __builtin_bit_cast(unsigned int, h);
}
__device__ __forceinline__ h8 ldh(const unsigned int* p) {
    uint4 u = *(const uint4*)p;
    return __builtin_bit_cast(h8, u);
}
#if __has_builtin(__builtin_amdgcn_fdot2)
__device__ __forceinline__ float dot2acc(unsigned int a, unsigned int b, float c) {
    return __builtin_amdgcn_fdot2(__builtin_bit_cast(h2, a), __builtin_bit_cast(h2, b), c, false);
}
__device__ __forceinline__ float dot2h(h2 a, h2 b, float c) {
    return __builtin_amdgcn_fdot2(a, b, c, false);
}
#else
__device__ __forceinline__ float dot2acc(unsigned int a, unsigned int b, float c) {
    h2 ha = __builtin_bit_cast(h2, a), hb = __builtin_bit_cast(h2, b);
    return fmaf((float)ha.y, (float)hb.y, fmaf((float)ha.x, (float)hb.x, c));
}
__device__ __forceinline__ float dot2h(h2 a, h2 b, float c) {
    return fmaf((float)a.y, (float)b.y, fmaf((float)a.x, (float)b.x, c));
}
#endif
#define H2C(v) ((h2){(_Float16)(v), (_Float16)(v)})
// GELU on a PAIR in packed f16 (v_pk_* ops). Odd-poly fit of erf(x/sqrt2),
// |x|<=3, |err|<=3e-3 f32 + <=4e-3 f16 Horner. Result ready for LDS store.
__device__ __forceinline__ unsigned int gelu2(float a, float b) {
    h2 xp = __builtin_bit_cast(h2, pkh(a, b));
#if __has_builtin(__builtin_elementwise_max) && __has_builtin(__builtin_elementwise_min)
    h2 xc = __builtin_elementwise_min(__builtin_elementwise_max(xp, H2C(-3.0f)), H2C(3.0f));
#else
    h2 xc = __builtin_bit_cast(h2, pkh(fminf(fmaxf(a, -3.0f), 3.0f),
                                       fminf(fmaxf(b, -3.0f), 3.0f)));
#endif
    h2 u = xc * xc;
    h2 p = H2C(4.80757e-5f);
    p = p * u + H2C(-1.40632e-3f);
    p = p * u + H2C(1.75795e-2f);
    p = p * u + H2C(-1.30947e-1f);
    p = p * u + H2C(7.9714e-1f);
    h2 hx = xp * H2C(0.5f);
    h2 r  = (hx * xc) * p + hx;                  // 0.5x(1 + xc*P(u))
    return __builtin_bit_cast(unsigned int, r);
}
__device__ __forceinline__ int permc(int p) {        // head-local sigma pairs
    int h = (p & 15) >> 2, j = p & 3, hi = p >> 4;
    return 8*h + 2*j + hi;
}
__device__ __forceinline__ int rkey(int row) {       // bank-spread group key
    return ((row >> 1) + (row >> 3)) & 3;
}
// LN over the packed-f16 residual X2[16] (sigma pairs: word w = cols (w, w+16)).
__device__ __forceinline__ void ln_write(const h2* X2, unsigned int* base, int row) {
    const h2 one = H2C(1.0f);
    float mu = 0.f;
    #pragma unroll
    for (int w = 0; w < 16; ++w) mu = dot2h(X2[w], one, mu);
    mu *= 0.03125f;
    h2 mu2 = __builtin_bit_cast(h2, pkh(mu, mu));
    float var = 0.f;
    #pragma unroll
    for (int w = 0; w < 16; ++w) { h2 d = X2[w] - mu2; var = dot2h(d, d, var); }
    var *= 0.03125f;
    float rs = rsqrtf(var + 1e-5f), b = -mu * rs;
    h2 rs2 = __builtin_bit_cast(h2, pkh(rs, rs));
    h2 b2  = __builtin_bit_cast(h2, pkh(b, b));
    unsigned int* rp = base + row * STR;
    const int k = rkey(row);
    #pragma unroll
    for (int g = 0; g < 4; ++g) {
        uint4 w;
        w.x = __builtin_bit_cast(unsigned int, X2[4*g+0] * rs2 + b2);
        w.y = __builtin_bit_cast(unsigned int, X2[4*g+1] * rs2 + b2);
        w.z = __builtin_bit_cast(unsigned int, X2[4*g+2] * rs2 + b2);
        w.w = __builtin_bit_cast(unsigned int, X2[4*g+3] * rs2 + b2);
        *(uint4*)&rp[(g ^ k) << 2] = w;
    }
}

// ---- prep: pre-pack all weights (f16, transposed, head-permuted) into ws ----
__global__ __launch_bounds__(64) void prep(
    const float* __restrict__ temb, const float* __restrict__ wq,
    const float* __restrict__ wk, const float* __restrict__ wv,
    const float* __restrict__ wo, const float* __restrict__ w1,
    const float* __restrict__ w2, unsigned int* __restrict__ ws)
{
    const int part = blockIdx.x;          // 0..24
    const int t = threadIdx.x;
    if (part == 24) {                     // TE tile
        for (int i = t; i < 256; i += 64) {
            int c = i >> 4, w = i & 15;
            ws[12288 + i] = (c < VOC) ? pkh(temb[c*32 + w], temb[c*32 + w + 16]) : 0u;
        }
        return;
    }
    const int L = part / 12, m = part % 12;
    unsigned int* o = ws + L * 6144;
    for (int i = t; i < 512; i += 64) {
        int c = i >> 4, w = i & 15;
        if (m < 3) {
            const float* M = (m == 0 ? wq : (m == 1 ? wk : wv)) + L*1024;
            int pc = permc(c);
            o[m*512 + i] = pkh(M[w*32 + pc], M[(w+16)*32 + pc]);
        } else if (m == 3) {
            const float* M = wo + L*1024;
            o[1536 + i] = pkh(M[permc(w)*32 + c], M[permc(w+16)*32 + c]);
        } else if (m < 8) {
            int q = m - 4;
            const float* M = w1 + L*4096;
            o[2048 + q*1024 + i] = pkh(M[w*128 + 32*q + c], M[(w+16)*128 + 32*q + c]);
        } else {
            int q = m - 8;
            const float* M = w2 + L*4096;
            o[2048 + q*1024 + 512 + i] = pkh(M[(32*q+w)*32 + c], M[(32*q+16+w)*32 + c]);
        }
    }
}

// w=3 spill-free. Critical resource = per-CU LDS pipe; conflicts (13.4M, ~22us)
// traced to tile-writes hitting one 16-bank half at stride 16 -> stride 20 fix.
__global__ __launch_bounds__(THREADS, 3)
void tf_mfma(const int* __restrict__ toks, const float* __restrict__ temb,
             const float* __restrict__ pemb, const unsigned int* __restrict__ ws,
             float* __restrict__ out, int nelem)
{
    __shared__ unsigned int S[SMEM_U32];
    const int tid  = threadIdx.x;
    const int lane = tid & 63;
    const int wid  = tid >> 6;
    const int llo  = lane & 15, lhi = lane >> 4;
    const int boff = 4 * lhi;
    int le = lane / 6;
    int s  = lane - le * 6;
    if (le > 9) { le = 9; s = 5; }                   // 4 dup lanes/wave (in-bounds)
    const int rb   = wid*64 + le*6;                  // element's slot base (in-wave)
    const int myk  = rkey(tid);
    const int elem = blockIdx.x * ELB + wid*10 + le;
    const f32x4 zz = {0.f, 0.f, 0.f, 0.f};

    h2 X2[16];                                       // residual stream, packed f16 sigma pairs
    {
        const int ti  = (elem < nelem) ? (elem*SEQ + s) : 0;
        const int tok = toks[ti];
        #pragma unroll
        for (int g = 0; g < 4; ++g) {
            float4 alo = *(const float4*)&temb[tok*32 + 4*g];
            float4 ahi = *(const float4*)&temb[tok*32 + 16 + 4*g];
            float4 plo = *(const float4*)&pemb[s*32 + 4*g];
            float4 phi = *(const float4*)&pemb[s*32 + 16 + 4*g];
            X2[4*g+0] = __builtin_bit_cast(h2, pkh(alo.x + plo.x, ahi.x + phi.x));
            X2[4*g+1] = __builtin_bit_cast(h2, pkh(alo.y + plo.y, ahi.y + phi.y));
            X2[4*g+2] = __builtin_bit_cast(h2, pkh(alo.z + plo.z, ahi.z + phi.z));
            X2[4*g+3] = __builtin_bit_cast(h2, pkh(alo.w + plo.w, ahi.w + phi.w));
        }
    }

    #pragma unroll 1
    for (int L = 0; L < NL; ++L) {
        const unsigned int* wsL = ws + L * 6144;

        ln_write(X2, &S[XN], tid);                   // Xn (own slot)

        // ---- QKV (weights direct from global; all LDS traffic in-wave) ----
        uint4 q4[4];
        {
            h8 bq0 = ldh(wsL +          llo    *16 + boff);
            h8 bq1 = ldh(wsL +         (llo+16)*16 + boff);
            h8 bk0 = ldh(wsL +  512 +   llo    *16 + boff);
            h8 bk1 = ldh(wsL +  512 +  (llo+16)*16 + boff);
            h8 bv0 = ldh(wsL + 1024 +   llo    *16 + boff);
            h8 bv1 = ldh(wsL + 1024 +  (llo+16)*16 + boff);
            h8 aa[4];
            #pragma unroll
            for (int j = 0; j < 4; ++j) {
                int rowa = wid*64 + j*16 + llo;
                aa[j] = ldh(&S[XN + rowa*STR + ((lhi ^ rkey(rowa)) << 2)]);
            }
            #pragma unroll
            for (int j = 0; j < 4; ++j) {            // K -> KP
                f32x4 k0 = __builtin_amdgcn_mfma_f32_16x16x32_f16(aa[j], bk0, zz, 0,0,0);
                f32x4 k1 = __builtin_amdgcn_mfma_f32_16x16x32_f16(aa[j], bk1, zz, 0,0,0);
                int rowb = wid*64 + j*16 + lhi*4;
                #pragma unroll
                for (int rg = 0; rg < 4; ++rg) {
                    int row = rowb + rg;
                    S[KP + row*STR + (((llo >> 2) ^ rkey(row)) << 2) + (llo & 3)] = pkh(k0[rg], k1[rg]);
                }
            }
            #pragma unroll
            for (int j = 0; j < 4; ++j) {            // Q -> XN (over Xn; aa read done)
                f32x4 qa = __builtin_amdgcn_mfma_f32_16x16x32_f16(aa[j], bq0, zz, 0,0,0);
                f32x4 qb = __builtin_amdgcn_mfma_f32_16x16x32_f16(aa[j], bq1, zz, 0,0,0);
                int rowb = wid*64 + j*16 + lhi*4;
                #pragma unroll
                for (int rg = 0; rg < 4; ++rg) {
                    int row = rowb + rg;
                    S[XN + row*STR + (((llo >> 2) ^ rkey(row)) << 2) + (llo & 3)] = pkh(qa[rg], qb[rg]);
                }
            }
            #pragma unroll
            for (int h = 0; h < 4; ++h)              // own-row Q (in-wave RAW, in-order DS)
                q4[h] = *(const uint4*)&S[XN + tid*STR + ((h ^ myk) << 2)];
            #pragma unroll
            for (int j = 0; j < 4; ++j) {            // V -> XN (over Q; q4 reads issued)
                f32x4 v0 = __builtin_amdgcn_mfma_f32_16x16x32_f16(aa[j], bv0, zz, 0,0,0);
                f32x4 v1 = __builtin_amdgcn_mfma_f32_16x16x32_f16(aa[j], bv1, zz, 0,0,0);
                int rowb = wid*64 + j*16 + lhi*4;
                #pragma unroll
                for (int rg = 0; rg < 4; ++rg) {
                    int row = rowb + rg;
                    S[XN + row*STR + (((llo >> 2) ^ rkey(row)) << 2) + (llo & 3)] = pkh(v0[rg], v1[rg]);
                }
            }
        }

        // ---- attention: ONLINE scores+PV in one pass ----
        // exp2 with folded scale: 0.35355339*log2(e) = 0.51006975. exp2(-1e30)=0 masks.
        {
            float den[4] = {0.f, 0.f, 0.f, 0.f};
            h2 O[16];
            #pragma unroll
            for (int w = 0; w < 16; ++w) O[w] = __builtin_bit_cast(h2, 0u);
            #pragma unroll
            for (int t = 0; t < SEQ; ++t) {
                int krow = rb + t;
                const unsigned int* kr = &S[KP + krow*STR];
                const unsigned int* vr = &S[XN + krow*STR];
                int kk4 = rkey(krow);
                float msk = (t <= s) ? 0.f : -1e30f;
                #pragma unroll
                for (int h = 0; h < 4; ++h) {
                    uint4 kk = *(const uint4*)&kr[(h ^ kk4) << 2];
                    float d = dot2acc(q4[h].x, kk.x, 0.f);
                    d = dot2acc(q4[h].y, kk.y, d);
                    d = dot2acc(q4[h].z, kk.z, d);
                    d = dot2acc(q4[h].w, kk.w, d);
                    float e = exp2f(fmaf(d, 0.51006975f, msk));
                    den[h] += e;
                    h2 wg2 = __builtin_bit_cast(h2, pkh(e, e));
                    uint4 vv = *(const uint4*)&vr[(h ^ kk4) << 2];
                    O[4*h+0] += __builtin_bit_cast(h2, vv.x) * wg2;
                    O[4*h+1] += __builtin_bit_cast(h2, vv.y) * wg2;
                    O[4*h+2] += __builtin_bit_cast(h2, vv.z) * wg2;
                    O[4*h+3] += __builtin_bit_cast(h2, vv.w) * wg2;
                }
            }
            #pragma unroll
            for (int h = 0; h < 4; ++h) {            // normalize
                float rdh = __builtin_amdgcn_rcpf(den[h]);
                h2 rr = __builtin_bit_cast(h2, pkh(rdh, rdh));
                O[4*h+0] *= rr; O[4*h+1] *= rr; O[4*h+2] *= rr; O[4*h+3] *= rr;
            }
            #pragma unroll
            for (int g = 0; g < 4; ++g) {            // O -> KP own row (over K; reads done)
                uint4 w;
                w.x = __builtin_bit_cast(unsigned int, O[4*g+0]);
                w.y = __builtin_bit_cast(unsigned int, O[4*g+1]);
                w.z = __builtin_bit_cast(unsigned int, O[4*g+2]);
                w.w = __builtin_bit_cast(unsigned int, O[4*g+3]);
                *(uint4*)&S[KP + tid*STR + ((g ^ myk) << 2)] = w;
            }
        }

        // ---- O.Wo: A=KP(O) -> D=XN (over V; PV reads issued) ----
        {
            h8 bo0 = ldh(wsL + 1536 +  llo    *16 + boff);
            h8 bo1 = ldh(wsL + 1536 + (llo+16)*16 + boff);
            #pragma unroll
            for (int j = 0; j < 4; ++j) {
                int rowa = wid*64 + j*16 + llo;
                h8 a = ldh(&S[KP + rowa*STR + ((lhi ^ rkey(rowa)) << 2)]);
                f32x4 o0 = __builtin_amdgcn_mfma_f32_16x16x32_f16(a, bo0, zz, 0,0,0);
                f32x4 o1 = __builtin_amdgcn_mfma_f32_16x16x32_f16(a, bo1, zz, 0,0,0);
                int rowb = wid*64 + j*16 + lhi*4;
                #pragma unroll
                for (int rg = 0; rg < 4; ++rg) {
                    int row = rowb + rg;
                    S[XN + row*STR + (((llo >> 2) ^ rkey(row)) << 2) + (llo & 3)] = pkh(o0[rg], o1[rg]);
                }
            }
        }
        #pragma unroll
        for (int g = 0; g < 4; ++g) {                // residual (own slot, packed adds)
            uint4 v = *(const uint4*)&S[XN + tid*STR + ((g ^ myk) << 2)];
            X2[4*g+0] += __builtin_bit_cast(h2, v.x);
            X2[4*g+1] += __builtin_bit_cast(h2, v.y);
            X2[4*g+2] += __builtin_bit_cast(h2, v.z);
            X2[4*g+3] += __builtin_bit_cast(h2, v.w);
        }
        ln_write(X2, &S[KP], tid);                   // Xn2 -> KP (over O; A reads issued)

        // ---- FFN: Xn2 A-frags hoisted (read once; saves 12 b128/layer). ----
        h8 aa2[4];
        #pragma unroll
        for (int j = 0; j < 4; ++j) {
            int rowa = wid*64 + j*16 + llo;
            aa2[j] = ldh(&S[KP + rowa*STR + ((lhi ^ rkey(rowa)) << 2)]);
        }
        f32x4 cf[4][2];
        #pragma unroll
        for (int j = 0; j < 4; ++j) { cf[j][0] = zz; cf[j][1] = zz; }
        #pragma unroll
        for (int q = 0; q < 4; ++q) {
            const unsigned int* wq4 = wsL + 2048 + q*1024;
            h8 b10 = ldh(wq4 +        llo    *16 + boff);
            h8 b11 = ldh(wq4 +       (llo+16)*16 + boff);
            h8 b20 = ldh(wq4 + 512 +  llo    *16 + boff);
            h8 b21 = ldh(wq4 + 512 + (llo+16)*16 + boff);
            #pragma unroll
            for (int j = 0; j < 4; ++j) {
                f32x4 h0 = __builtin_amdgcn_mfma_f32_16x16x32_f16(aa2[j], b10, zz, 0,0,0);
                f32x4 h1 = __builtin_amdgcn_mfma_f32_16x16x32_f16(aa2[j], b11, zz, 0,0,0);
                int rowb = wid*64 + j*16 + lhi*4;
                #pragma unroll
                for (int rg = 0; rg < 4; ++rg) {
                    int row = rowb + rg;
                    S[XN + row*STR + (((llo >> 2) ^ rkey(row)) << 2) + (llo & 3)] = gelu2(h0[rg], h1[rg]);
                }
            }
            #pragma unroll
            for (int j = 0; j < 4; ++j) {            // FFN2 (H rows in-wave)
                int rowa = wid*64 + j*16 + llo;
                h8 ah = ldh(&S[XN + rowa*STR + ((lhi ^ rkey(rowa)) << 2)]);
                cf[j][0] = __builtin_amdgcn_mfma_f32_16x16x32_f16(ah, b20, cf[j][0], 0,0,0);
                cf[j][1] = __builtin_amdgcn_mfma_f32_16x16x32_f16(ah, b21, cf[j][1], 0,0,0);
            }
        }
        #pragma unroll
        for (int j = 0; j < 4; ++j) {                // FFN2 out -> XN (over H)
            int rowb = wid*64 + j*16 + lhi*4;
            #pragma unroll
            for (int rg = 0; rg < 4; ++rg) {
                int row = rowb + rg;
                S[XN + row*STR + (((llo >> 2) ^ rkey(row)) << 2) + (llo & 3)] = pkh(cf[j][0][rg], cf[j][1][rg]);
            }
        }
        #pragma unroll
        for (int g = 0; g < 4; ++g) {                // residual (own slot, packed adds)
            uint4 v = *(const uint4*)&S[XN + tid*STR + ((g ^ myk) << 2)];
            X2[4*g+0] += __builtin_bit_cast(h2, v.x);
            X2[4*g+1] += __builtin_bit_cast(h2, v.y);
            X2[4*g+2] += __builtin_bit_cast(h2, v.z);
            X2[4*g+3] += __builtin_bit_cast(h2, v.w);
        }
    }

    // ---- final LN + weight-tied logits ----
    ln_write(X2, &S[XN], tid);
    {
        h8 bt = ldh(ws + 12288 + llo*16 + boff);
        #pragma unroll
        for (int j = 0; j < 4; ++j) {
            int rowa = wid*64 + j*16 + llo;
            h8 a = ldh(&S[XN + rowa*STR + ((lhi ^ rkey(rowa)) << 2)]);
            f32x4 lg = __builtin_amdgcn_mfma_f32_16x16x32_f16(a, bt, zz, 0,0,0);
            int rowb = wid*64 + j*16 + lhi*4;
            #pragma unroll
            for (int rg = 0; rg < 4; ++rg) {
                int row = rowb + rg;
                S[KP + row*STR + (((llo >> 2) ^ rkey(row)) << 2) + (llo & 3)] = __float_as_uint(lg[rg]);
            }
        }
    }
    __syncthreads();                                 // the only barrier
    {
        const long long obase = (long long)blockIdx.x * (ELB*SEQ*VOC);   // 3600
        const long long tot   = (long long)nelem * (SEQ*VOC);
        for (int i = tid; i < ELB*SEQ*VOC; i += THREADS) {
            if (obase + i < tot) {
                int rl   = i / VOC, col = i - rl*VOC;
                int w    = rl / 60, r6 = rl - w*60;
                int slot = w*64 + r6;
                out[obase + i] = __uint_as_float(
                    S[KP + slot*STR + (((col >> 2) ^ rkey(slot)) << 2) + (col & 3)]);
            }
        }
    }
}

extern "C" void kernel_launch(void* const* d_in, const int* in_sizes, int n_in,
                              void* d_out, int out_size, void* d_ws, size_t ws_size,
                              hipStream_t stream) {
    const int*   toks = (const int*)  d_in[0];
    const float* temb = (const float*)d_in[1];
    const float* pemb = (const float*)d_in[2];
    const float* wq   = (const float*)d_in[3];
    const float* wk   = (const float*)d_in[4];
    const float* wv   = (const float*)d_in[5];
    const float* wo   = (const float*)d_in[6];
    const float* w1   = (const float*)d_in[7];
    const float* w2   = (const float*)d_in[8];
    unsigned int* ws  = (unsigned int*)d_ws;         // 12544 u32 = 50 KB used
    float* out = (float*)d_out;
    const int nelem = in_sizes[0] / SEQ;             // 131072
    const int nblk  = (nelem + ELB - 1) / ELB;       // 3277

    prep<<<dim3(25), dim3(64), 0, stream>>>(temb, wq, wk, wv, wo, w1, w2, ws);
    tf_mfma<<<dim3(nblk), dim3(THREADS), 0, stream>>>(toks, temb, pemb, ws, out, nelem);
}

// Round 18
// 141.291 us; speedup vs baseline: 1.0034x; 1.0034x over previous
//
#include <hip/hip_runtime.h>

#define SEQ 6
#define THREADS 256              // 4 waves; 10 elements per wave (60 active lanes)
#define ELB 40                   // elements per block
#define NL 2
#define VOC 15

typedef __attribute__((ext_vector_type(8))) _Float16 h8;
typedef __attribute__((ext_vector_type(2))) _Float16 h2;
typedef __attribute__((ext_vector_type(4))) float    f32x4;

// LDS: 2 pools x 8000 u32 = 31.25 KB. Element-padded layout:
//   addr(row) = wave*1000 + elem*100 + s*16   (elem = local 0..9, s = 0..5)
// Delta-elem = 100 = 4 mod 32 banks -> the 10 attention groups/wave spread over
// 8 bank windows (~2-way, free), vs stride-16's 96 = 0 mod 32 (all same window).
// 16B-group XOR key k(l) = ((l>>1)&3), l = 6*elem+s (wave term = 0 mod 4).
// Dup lanes (60..63) clamp to elem9/s5's address AND key -> identical writes.
// All offsets precomputed into regs once: zero per-layer address VALU.
#define XN 0          // Xn -> Q -> V -> OWo -> H -> FFN2
#define KP 4000       // K -> O -> Xn2 -> logits f32
#define SMEM_U32 8000

// ws layout (u32): per layer L at L*6144: Wq 0, Wk 512, Wv 1024, Wo 1536,
// quarter q: 2048+q*1024 (W1q at +0, W2q at +512). TE at 12288 (256).

__device__ __forceinline__ unsigned int pkh(float a, float b) {
    auto h = __builtin_amdgcn_cvt_pkrtz(a, b);
    return __builtin_bit_cast(unsigned int, h);
}
__device__ __forceinline__ h8 ldh(const unsigned int* p) {
    uint4 u = *(const uint4*)p;
    return __builtin_bit_cast(h8, u);
}
#if __has_builtin(__builtin_amdgcn_fdot2)
__device__ __forceinline__ float dot2acc(unsigned int a, unsigned int b, float c) {
    return __builtin_amdgcn_fdot2(__builtin_bit_cast(h2, a), __builtin_bit_cast(h2, b), c, false);
}
__device__ __forceinline__ float dot2h(h2 a, h2 b, float c) {
    return __builtin_amdgcn_fdot2(a, b, c, false);
}
#else
__device__ __forceinline__ float dot2acc(unsigned int a, unsigned int b, float c) {
    h2 ha = __builtin_bit_cast(h2, a), hb = __builtin_bit_cast(h2, b);
    return fmaf((float)ha.y, (float)hb.y, fmaf((float)ha.x, (float)hb.x, c));
}
__device__ __forceinline__ float dot2h(h2 a, h2 b, float c) {
    return fmaf((float)a.y, (float)b.y, fmaf((float)a.x, (float)b.x, c));
}
#endif
#define H2C(v) ((h2){(_Float16)(v), (_Float16)(v)})
// GELU on a PAIR in packed f16 (v_pk_* ops). Odd-poly fit of erf(x/sqrt2),
// |x|<=3, |err|<=3e-3 f32 + <=4e-3 f16 Horner. Result ready for LDS store.
__device__ __forceinline__ unsigned int gelu2(float a, float b) {
    h2 xp = __builtin_bit_cast(h2, pkh(a, b));
#if __has_builtin(__builtin_elementwise_max) && __has_builtin(__builtin_elementwise_min)
    h2 xc = __builtin_elementwise_min(__builtin_elementwise_max(xp, H2C(-3.0f)), H2C(3.0f));
#else
    h2 xc = __builtin_bit_cast(h2, pkh(fminf(fmaxf(a, -3.0f), 3.0f),
                                       fminf(fmaxf(b, -3.0f), 3.0f)));
#endif
    h2 u = xc * xc;
    h2 p = H2C(4.80757e-5f);
    p = p * u + H2C(-1.40632e-3f);
    p = p * u + H2C(1.75795e-2f);
    p = p * u + H2C(-1.30947e-1f);
    p = p * u + H2C(7.9714e-1f);
    h2 hx = xp * H2C(0.5f);
    h2 r  = (hx * xc) * p + hx;                  // 0.5x(1 + xc*P(u))
    return __builtin_bit_cast(unsigned int, r);
}
__device__ __forceinline__ int permc(int p) {        // head-local sigma pairs
    int h = (p & 15) >> 2, j = p & 3, hi = p >> 4;
    return 8*h + 2*j + hi;
}
// LN over the packed-f16 residual X2[16]; writes to precomputed slot pointer.
__device__ __forceinline__ void ln_write(const h2* X2, unsigned int* rp, int k) {
    const h2 one = H2C(1.0f);
    float mu = 0.f;
    #pragma unroll
    for (int w = 0; w < 16; ++w) mu = dot2h(X2[w], one, mu);
    mu *= 0.03125f;
    h2 mu2 = __builtin_bit_cast(h2, pkh(mu, mu));
    float var = 0.f;
    #pragma unroll
    for (int w = 0; w < 16; ++w) { h2 d = X2[w] - mu2; var = dot2h(d, d, var); }
    var *= 0.03125f;
    float rs = rsqrtf(var + 1e-5f), b = -mu * rs;
    h2 rs2 = __builtin_bit_cast(h2, pkh(rs, rs));
    h2 b2  = __builtin_bit_cast(h2, pkh(b, b));
    #pragma unroll
    for (int g = 0; g < 4; ++g) {
        uint4 w;
        w.x = __builtin_bit_cast(unsigned int, X2[4*g+0] * rs2 + b2);
        w.y = __builtin_bit_cast(unsigned int, X2[4*g+1] * rs2 + b2);
        w.z = __builtin_bit_cast(unsigned int, X2[4*g+2] * rs2 + b2);
        w.w = __builtin_bit_cast(unsigned int, X2[4*g+3] * rs2 + b2);
        *(uint4*)&rp[(g ^ k) << 2] = w;
    }
}

// ---- prep: pre-pack all weights (f16, transposed, head-permuted) into ws ----
__global__ __launch_bounds__(64) void prep(
    const float* __restrict__ temb, const float* __restrict__ wq,
    const float* __restrict__ wk, const float* __restrict__ wv,
    const float* __restrict__ wo, const float* __restrict__ w1,
    const float* __restrict__ w2, unsigned int* __restrict__ ws)
{
    const int part = blockIdx.x;          // 0..24
    const int t = threadIdx.x;
    if (part == 24) {                     // TE tile
        for (int i = t; i < 256; i += 64) {
            int c = i >> 4, w = i & 15;
            ws[12288 + i] = (c < VOC) ? pkh(temb[c*32 + w], temb[c*32 + w + 16]) : 0u;
        }
        return;
    }
    const int L = part / 12, m = part % 12;
    unsigned int* o = ws + L * 6144;
    for (int i = t; i < 512; i += 64) {
        int c = i >> 4, w = i & 15;
        if (m < 3) {
            const float* M = (m == 0 ? wq : (m == 1 ? wk : wv)) + L*1024;
            int pc = permc(c);
            o[m*512 + i] = pkh(M[w*32 + pc], M[(w+16)*32 + pc]);
        } else if (m == 3) {
            const float* M = wo + L*1024;
            o[1536 + i] = pkh(M[permc(w)*32 + c], M[permc(w+16)*32 + c]);
        } else if (m < 8) {
            int q = m - 4;
            const float* M = w1 + L*4096;
            o[2048 + q*1024 + i] = pkh(M[w*128 + 32*q + c], M[(w+16)*128 + 32*q + c]);
        } else {
            int q = m - 8;
            const float* M = w2 + L*4096;
            o[2048 + q*1024 + 512 + i] = pkh(M[(32*q+w)*32 + c], M[(32*q+16+w)*32 + c]);
        }
    }
}

// w=3 spill-free (proven). Critical resource = per-CU LDS pipe; this round
// fixes the attn-read bank aliasing via element-padded layout, offsets all
// precomputed (R17's per-site rkey VALU overhead eliminated).
__global__ __launch_bounds__(THREADS, 3)
void tf_mfma(const int* __restrict__ toks, const float* __restrict__ temb,
             const float* __restrict__ pemb, const unsigned int* __restrict__ ws,
             float* __restrict__ out, int nelem)
{
    __shared__ unsigned int S[SMEM_U32];
    const int tid  = threadIdx.x;
    const int lane = tid & 63;
    const int wid  = tid >> 6;
    const int llo  = lane & 15, lhi = lane >> 4;
    const int boff = 4 * lhi;
    int le = lane / 6;
    int s  = lane - le * 6;
    if (le > 9) { le = 9; s = 5; }                   // 4 dup lanes/wave
    const int le6  = le * 6;
    const int elem = blockIdx.x * ELB + wid*10 + le;
    const f32x4 zz = {0.f, 0.f, 0.f, 0.f};

    // ---- precomputed LDS offsets (loop-invariant; zero per-layer addr VALU) ----
    const int wb    = wid * 1000;
    const int myOff = wb + le*100 + s*16;
    const int myk   = ((le6 + s) >> 1) & 3;
    const int atnB  = wb + le*100;
    int sOff[16], aOff[4];
    #pragma unroll
    for (int j = 0; j < 4; ++j) {
        {   int l = j*16 + llo;                      // A-frag row (clamped like dups)
            int e9 = l / 6, ss = l - 6*e9; if (e9 > 9) { e9 = 9; ss = 5; }
            int k = ((e9*6 + ss) >> 1) & 3;
            aOff[j] = wb + e9*100 + ss*16 + ((lhi ^ k) << 2); }
        #pragma unroll
        for (int rg = 0; rg < 4; ++rg) {             // scatter row
            int l = j*16 + lhi*4 + rg;
            int e9 = l / 6, ss = l - 6*e9; if (e9 > 9) { e9 = 9; ss = 5; }
            int k = ((e9*6 + ss) >> 1) & 3;
            sOff[4*j + rg] = wb + e9*100 + ss*16 + ((((llo >> 2) ^ k)) << 2) + (llo & 3);
        }
    }

    h2 X2[16];                                       // residual stream, packed f16 sigma pairs
    {
        const int ti  = (elem < nelem) ? (elem*SEQ + s) : 0;
        const int tok = toks[ti];
        #pragma unroll
        for (int g = 0; g < 4; ++g) {
            float4 alo = *(const float4*)&temb[tok*32 + 4*g];
            float4 ahi = *(const float4*)&temb[tok*32 + 16 + 4*g];
            float4 plo = *(const float4*)&pemb[s*32 + 4*g];
            float4 phi = *(const float4*)&pemb[s*32 + 16 + 4*g];
            X2[4*g+0] = __builtin_bit_cast(h2, pkh(alo.x + plo.x, ahi.x + phi.x));
            X2[4*g+1] = __builtin_bit_cast(h2, pkh(alo.y + plo.y, ahi.y + phi.y));
            X2[4*g+2] = __builtin_bit_cast(h2, pkh(alo.z + plo.z, ahi.z + phi.z));
            X2[4*g+3] = __builtin_bit_cast(h2, pkh(alo.w + plo.w, ahi.w + phi.w));
        }
    }

    #pragma unroll 1
    for (int L = 0; L < NL; ++L) {
        const unsigned int* wsL = ws + L * 6144;

        ln_write(X2, &S[XN + myOff], myk);           // Xn (own slot)

        // ---- QKV (weights direct from global; all LDS traffic in-wave) ----
        uint4 q4[4];
        {
            h8 bq0 = ldh(wsL +          llo    *16 + boff);
            h8 bq1 = ldh(wsL +         (llo+16)*16 + boff);
            h8 bk0 = ldh(wsL +  512 +   llo    *16 + boff);
            h8 bk1 = ldh(wsL +  512 +  (llo+16)*16 + boff);
            h8 bv0 = ldh(wsL + 1024 +   llo    *16 + boff);
            h8 bv1 = ldh(wsL + 1024 +  (llo+16)*16 + boff);
            h8 aa[4];
            #pragma unroll
            for (int j = 0; j < 4; ++j) aa[j] = ldh(&S[XN + aOff[j]]);
            #pragma unroll
            for (int j = 0; j < 4; ++j) {            // K -> KP
                f32x4 k0 = __builtin_amdgcn_mfma_f32_16x16x32_f16(aa[j], bk0, zz, 0,0,0);
                f32x4 k1 = __builtin_amdgcn_mfma_f32_16x16x32_f16(aa[j], bk1, zz, 0,0,0);
                #pragma unroll
                for (int rg = 0; rg < 4; ++rg)
                    S[KP + sOff[4*j+rg]] = pkh(k0[rg], k1[rg]);
            }
            #pragma unroll
            for (int j = 0; j < 4; ++j) {            // Q -> XN (over Xn; aa read done)
                f32x4 qa = __builtin_amdgcn_mfma_f32_16x16x32_f16(aa[j], bq0, zz, 0,0,0);
                f32x4 qb = __builtin_amdgcn_mfma_f32_16x16x32_f16(aa[j], bq1, zz, 0,0,0);
                #pragma unroll
                for (int rg = 0; rg < 4; ++rg)
                    S[XN + sOff[4*j+rg]] = pkh(qa[rg], qb[rg]);
            }
            #pragma unroll
            for (int h = 0; h < 4; ++h)              // own-row Q (in-wave RAW, in-order DS)
                q4[h] = *(const uint4*)&S[XN + myOff + ((h ^ myk) << 2)];
            #pragma unroll
            for (int j = 0; j < 4; ++j) {            // V -> XN (over Q; q4 reads issued)
                f32x4 v0 = __builtin_amdgcn_mfma_f32_16x16x32_f16(aa[j], bv0, zz, 0,0,0);
                f32x4 v1 = __builtin_amdgcn_mfma_f32_16x16x32_f16(aa[j], bv1, zz, 0,0,0);
                #pragma unroll
                for (int rg = 0; rg < 4; ++rg)
                    S[XN + sOff[4*j+rg]] = pkh(v0[rg], v1[rg]);
            }
        }

        // ---- attention: ONLINE scores+PV in one pass ----
        // exp2 with folded scale: 0.35355339*log2(e) = 0.51006975. exp2(-1e30)=0 masks.
        {
            float den[4] = {0.f, 0.f, 0.f, 0.f};
            h2 O[16];
            #pragma unroll
            for (int w = 0; w < 16; ++w) O[w] = __builtin_bit_cast(h2, 0u);
            #pragma unroll
            for (int t = 0; t < SEQ; ++t) {
                const unsigned int* kr = &S[KP + atnB + t*16];
                const unsigned int* vr = &S[XN + atnB + t*16];
                int kk4 = ((le6 + t) >> 1) & 3;
                float msk = (t <= s) ? 0.f : -1e30f;
                #pragma unroll
                for (int h = 0; h < 4; ++h) {
                    uint4 kk = *(const uint4*)&kr[(h ^ kk4) << 2];
                    float d = dot2acc(q4[h].x, kk.x, 0.f);
                    d = dot2acc(q4[h].y, kk.y, d);
                    d = dot2acc(q4[h].z, kk.z, d);
                    d = dot2acc(q4[h].w, kk.w, d);
                    float e = exp2f(fmaf(d, 0.51006975f, msk));
                    den[h] += e;
                    h2 wg2 = __builtin_bit_cast(h2, pkh(e, e));
                    uint4 vv = *(const uint4*)&vr[(h ^ kk4) << 2];
                    O[4*h+0] += __builtin_bit_cast(h2, vv.x) * wg2;
                    O[4*h+1] += __builtin_bit_cast(h2, vv.y) * wg2;
                    O[4*h+2] += __builtin_bit_cast(h2, vv.z) * wg2;
                    O[4*h+3] += __builtin_bit_cast(h2, vv.w) * wg2;
                }
            }
            #pragma unroll
            for (int h = 0; h < 4; ++h) {            // normalize
                float rdh = __builtin_amdgcn_rcpf(den[h]);
                h2 rr = __builtin_bit_cast(h2, pkh(rdh, rdh));
                O[4*h+0] *= rr; O[4*h+1] *= rr; O[4*h+2] *= rr; O[4*h+3] *= rr;
            }
            #pragma unroll
            for (int g = 0; g < 4; ++g) {            // O -> KP own slot (over K; reads done)
                uint4 w;
                w.x = __builtin_bit_cast(unsigned int, O[4*g+0]);
                w.y = __builtin_bit_cast(unsigned int, O[4*g+1]);
                w.z = __builtin_bit_cast(unsigned int, O[4*g+2]);
                w.w = __builtin_bit_cast(unsigned int, O[4*g+3]);
                *(uint4*)&S[KP + myOff + ((g ^ myk) << 2)] = w;
            }
        }

        // ---- O.Wo: A=KP(O) -> D=XN (over V; PV reads issued) ----
        {
            h8 bo0 = ldh(wsL + 1536 +  llo    *16 + boff);
            h8 bo1 = ldh(wsL + 1536 + (llo+16)*16 + boff);
            #pragma unroll
            for (int j = 0; j < 4; ++j) {
                h8 a = ldh(&S[KP + aOff[j]]);
                f32x4 o0 = __builtin_amdgcn_mfma_f32_16x16x32_f16(a, bo0, zz, 0,0,0);
                f32x4 o1 = __builtin_amdgcn_mfma_f32_16x16x32_f16(a, bo1, zz, 0,0,0);
                #pragma unroll
                for (int rg = 0; rg < 4; ++rg)
                    S[XN + sOff[4*j+rg]] = pkh(o0[rg], o1[rg]);
            }
        }
        #pragma unroll
        for (int g = 0; g < 4; ++g) {                // residual (own slot, packed adds)
            uint4 v = *(const uint4*)&S[XN + myOff + ((g ^ myk) << 2)];
            X2[4*g+0] += __builtin_bit_cast(h2, v.x);
            X2[4*g+1] += __builtin_bit_cast(h2, v.y);
            X2[4*g+2] += __builtin_bit_cast(h2, v.z);
            X2[4*g+3] += __builtin_bit_cast(h2, v.w);
        }
        ln_write(X2, &S[KP + myOff], myk);           // Xn2 -> KP (over O; A reads issued)

        // ---- FFN: Xn2 A-frags hoisted (read once; saves 12 b128/layer). ----
        h8 aa2[4];
        #pragma unroll
        for (int j = 0; j < 4; ++j) aa2[j] = ldh(&S[KP + aOff[j]]);
        f32x4 cf[4][2];
        #pragma unroll
        for (int j = 0; j < 4; ++j) { cf[j][0] = zz; cf[j][1] = zz; }
        #pragma unroll
        for (int q = 0; q < 4; ++q) {
            const unsigned int* wq4 = wsL + 2048 + q*1024;
            h8 b10 = ldh(wq4 +        llo    *16 + boff);
            h8 b11 = ldh(wq4 +       (llo+16)*16 + boff);
            h8 b20 = ldh(wq4 + 512 +  llo    *16 + boff);
            h8 b21 = ldh(wq4 + 512 + (llo+16)*16 + boff);
            #pragma unroll
            for (int j = 0; j < 4; ++j) {
                f32x4 h0 = __builtin_amdgcn_mfma_f32_16x16x32_f16(aa2[j], b10, zz, 0,0,0);
                f32x4 h1 = __builtin_amdgcn_mfma_f32_16x16x32_f16(aa2[j], b11, zz, 0,0,0);
                #pragma unroll
                for (int rg = 0; rg < 4; ++rg)
                    S[XN + sOff[4*j+rg]] = gelu2(h0[rg], h1[rg]);
            }
            #pragma unroll
            for (int j = 0; j < 4; ++j) {            // FFN2 (H rows in-wave)
                h8 ah = ldh(&S[XN + aOff[j]]);
                cf[j][0] = __builtin_amdgcn_mfma_f32_16x16x32_f16(ah, b20, cf[j][0], 0,0,0);
                cf[j][1] = __builtin_amdgcn_mfma_f32_16x16x32_f16(ah, b21, cf[j][1], 0,0,0);
            }
        }
        #pragma unroll
        for (int j = 0; j < 4; ++j) {                // FFN2 out -> XN (over H)
            #pragma unroll
            for (int rg = 0; rg < 4; ++rg)
                S[XN + sOff[4*j+rg]] = pkh(cf[j][0][rg], cf[j][1][rg]);
        }
        #pragma unroll
        for (int g = 0; g < 4; ++g) {                // residual (own slot, packed adds)
            uint4 v = *(const uint4*)&S[XN + myOff + ((g ^ myk) << 2)];
            X2[4*g+0] += __builtin_bit_cast(h2, v.x);
            X2[4*g+1] += __builtin_bit_cast(h2, v.y);
            X2[4*g+2] += __builtin_bit_cast(h2, v.z);
            X2[4*g+3] += __builtin_bit_cast(h2, v.w);
        }
    }

    // ---- final LN + weight-tied logits ----
    ln_write(X2, &S[XN + myOff], myk);
    {
        h8 bt = ldh(ws + 12288 + llo*16 + boff);
        #pragma unroll
        for (int j = 0; j < 4; ++j) {
            h8 a = ldh(&S[XN + aOff[j]]);
            f32x4 lg = __builtin_amdgcn_mfma_f32_16x16x32_f16(a, bt, zz, 0,0,0);
            #pragma unroll
            for (int rg = 0; rg < 4; ++rg)
                S[KP + sOff[4*j+rg]] = __float_as_uint(lg[rg]);
        }
    }
    __syncthreads();                                 // the only barrier
    {
        const long long obase = (long long)blockIdx.x * (ELB*SEQ*VOC);   // 3600
        const long long tot   = (long long)nelem * (SEQ*VOC);
        for (int i = tid; i < ELB*SEQ*VOC; i += THREADS) {
            if (obase + i < tot) {
                int rl  = i / VOC, col = i - rl*VOC;
                int w   = rl / 60, r6 = rl - w*60;     // r6 in 0..59
                int e   = r6 / 6,  ss = r6 - e*6;
                int k   = (r6 >> 1) & 3;
                int off = w*1000 + e*100 + ss*16;
                out[obase + i] = __uint_as_float(
                    S[KP + off + ((((col >> 2) ^ k)) << 2) + (col & 3)]);
            }
        }
    }
}

extern "C" void kernel_launch(void* const* d_in, const int* in_sizes, int n_in,
                              void* d_out, int out_size, void* d_ws, size_t ws_size,
                              hipStream_t stream) {
    const int*   toks = (const int*)  d_in[0];
    const float* temb = (const float*)d_in[1];
    const float* pemb = (const float*)d_in[2];
    const float* wq   = (const float*)d_in[3];
    const float* wk   = (const float*)d_in[4];
    const float* wv   = (const float*)d_in[5];
    const float* wo   = (const float*)d_in[6];
    const float* w1   = (const float*)d_in[7];
    const float* w2   = (const float*)d_in[8];
    unsigned int* ws  = (unsigned int*)d_ws;         // 12544 u32 = 50 KB used
    float* out = (float*)d_out;
    const int nelem = in_sizes[0] / SEQ;             // 131072
    const int nblk  = (nelem + ELB - 1) / ELB;       // 3277

    prep<<<dim3(25), dim3(64), 0, stream>>>(temb, wq, wk, wv, wo, w1, w2, ws);
    tf_mfma<<<dim3(nblk), dim3(THREADS), 0, stream>>>(toks, temb, pemb, ws, out, nelem);
}

// Round 19
// 132.613 us; speedup vs baseline: 1.0690x; 1.0654x over previous
//
#include <hip/hip_runtime.h>

#define SEQ 6
#define THREADS 256              // 4 waves; 10 elements per wave (60 active lanes)
#define ELB 40                   // elements per block
#define NL 2
#define VOC 15

typedef __attribute__((ext_vector_type(8))) _Float16 h8;
typedef __attribute__((ext_vector_type(2))) _Float16 h2;
typedef __attribute__((ext_vector_type(4))) float    f32x4;

// LDS: 2 pools x 256 slots x 16 u32, XOR-swizzled 16B groups. 8192 u32 = 32 KB.
// R16 layout exactly (best measured). NEW this round: MFMA operands swapped
// (D = W·Act instead of Act·W) so lane llo holds 4 consecutive sigma-words of
// act row llo -> every tile output is ONE ds_write_b128 at the A-frag address
// (144 b32 scatters/thread/layer -> 36 b128). LDS content is bit-identical.
#define XN 0          // Xn -> Q -> V -> OWo -> H -> FFN2
#define KP 4096       // K -> O -> Xn2 -> logits f32
#define SMEM_U32 8192

// ws layout (u32): per layer L at L*6144: Wq 0, Wk 512, Wv 1024, Wo 1536,
// quarter q: 2048+q*1024 (W1q at +0, W2q at +512). TE at 12288 (256).

__device__ __forceinline__ unsigned int pkh(float a, float b) {
    auto h = __builtin_amdgcn_cvt_pkrtz(a, b);
    return __builtin_bit_cast(unsigned int, h);
}
__device__ __forceinline__ h8 ldh(const unsigned int* p) {
    uint4 u = *(const uint4*)p;
    return __builtin_bit_cast(h8, u);
}
#if __has_builtin(__builtin_amdgcn_fdot2)
__device__ __forceinline__ float dot2acc(unsigned int a, unsigned int b, float c) {
    return __builtin_amdgcn_fdot2(__builtin_bit_cast(h2, a), __builtin_bit_cast(h2, b), c, false);
}
__device__ __forceinline__ float dot2h(h2 a, h2 b, float c) {
    return __builtin_amdgcn_fdot2(a, b, c, false);
}
#else
__device__ __forceinline__ float dot2acc(unsigned int a, unsigned int b, float c) {
    h2 ha = __builtin_bit_cast(h2, a), hb = __builtin_bit_cast(h2, b);
    return fmaf((float)ha.y, (float)hb.y, fmaf((float)ha.x, (float)hb.x, c));
}
__device__ __forceinline__ float dot2h(h2 a, h2 b, float c) {
    return fmaf((float)a.y, (float)b.y, fmaf((float)a.x, (float)b.x, c));
}
#endif
#define H2C(v) ((h2){(_Float16)(v), (_Float16)(v)})
// GELU on a PAIR in packed f16 (v_pk_* ops). Odd-poly fit of erf(x/sqrt2),
// |x|<=3, |err|<=3e-3 f32 + <=4e-3 f16 Horner. Result ready for LDS store.
__device__ __forceinline__ unsigned int gelu2(float a, float b) {
    h2 xp = __builtin_bit_cast(h2, pkh(a, b));
#if __has_builtin(__builtin_elementwise_max) && __has_builtin(__builtin_elementwise_min)
    h2 xc = __builtin_elementwise_min(__builtin_elementwise_max(xp, H2C(-3.0f)), H2C(3.0f));
#else
    h2 xc = __builtin_bit_cast(h2, pkh(fminf(fmaxf(a, -3.0f), 3.0f),
                                       fminf(fmaxf(b, -3.0f), 3.0f)));
#endif
    h2 u = xc * xc;
    h2 p = H2C(4.80757e-5f);
    p = p * u + H2C(-1.40632e-3f);
    p = p * u + H2C(1.75795e-2f);
    p = p * u + H2C(-1.30947e-1f);
    p = p * u + H2C(7.9714e-1f);
    h2 hx = xp * H2C(0.5f);
    h2 r  = (hx * xc) * p + hx;                  // 0.5x(1 + xc*P(u))
    return __builtin_bit_cast(unsigned int, r);
}
__device__ __forceinline__ int permc(int p) {        // head-local sigma pairs
    int h = (p & 15) >> 2, j = p & 3, hi = p >> 4;
    return 8*h + 2*j + hi;
}
__device__ __forceinline__ int swg(int row, int g) { // swizzled 16B-group offset
    return ((g ^ ((row >> 1) & 3)) << 2);
}
// LN over the packed-f16 residual X2[16] (sigma pairs: word w = cols (w, w+16)).
__device__ __forceinline__ void ln_write(const h2* X2, unsigned int* base, int row) {
    const h2 one = H2C(1.0f);
    float mu = 0.f;
    #pragma unroll
    for (int w = 0; w < 16; ++w) mu = dot2h(X2[w], one, mu);
    mu *= 0.03125f;
    h2 mu2 = __builtin_bit_cast(h2, pkh(mu, mu));
    float var = 0.f;
    #pragma unroll
    for (int w = 0; w < 16; ++w) { h2 d = X2[w] - mu2; var = dot2h(d, d, var); }
    var *= 0.03125f;
    float rs = rsqrtf(var + 1e-5f), b = -mu * rs;
    h2 rs2 = __builtin_bit_cast(h2, pkh(rs, rs));
    h2 b2  = __builtin_bit_cast(h2, pkh(b, b));
    unsigned int* rp = base + row * 16;
    const int k = (row >> 1) & 3;
    #pragma unroll
    for (int g = 0; g < 4; ++g) {
        uint4 w;
        w.x = __builtin_bit_cast(unsigned int, X2[4*g+0] * rs2 + b2);
        w.y = __builtin_bit_cast(unsigned int, X2[4*g+1] * rs2 + b2);
        w.z = __builtin_bit_cast(unsigned int, X2[4*g+2] * rs2 + b2);
        w.w = __builtin_bit_cast(unsigned int, X2[4*g+3] * rs2 + b2);
        *(uint4*)&rp[(g ^ k) << 2] = w;
    }
}

// ---- prep: pre-pack all weights (f16, transposed, head-permuted) into ws ----
__global__ __launch_bounds__(64) void prep(
    const float* __restrict__ temb, const float* __restrict__ wq,
    const float* __restrict__ wk, const float* __restrict__ wv,
    const float* __restrict__ wo, const float* __restrict__ w1,
    const float* __restrict__ w2, unsigned int* __restrict__ ws)
{
    const int part = blockIdx.x;          // 0..24
    const int t = threadIdx.x;
    if (part == 24) {                     // TE tile
        for (int i = t; i < 256; i += 64) {
            int c = i >> 4, w = i & 15;
            ws[12288 + i] = (c < VOC) ? pkh(temb[c*32 + w], temb[c*32 + w + 16]) : 0u;
        }
        return;
    }
    const int L = part / 12, m = part % 12;
    unsigned int* o = ws + L * 6144;
    for (int i = t; i < 512; i += 64) {
        int c = i >> 4, w = i & 15;
        if (m < 3) {
            const float* M = (m == 0 ? wq : (m == 1 ? wk : wv)) + L*1024;
            int pc = permc(c);
            o[m*512 + i] = pkh(M[w*32 + pc], M[(w+16)*32 + pc]);
        } else if (m == 3) {
            const float* M = wo + L*1024;
            o[1536 + i] = pkh(M[permc(w)*32 + c], M[permc(w+16)*32 + c]);
        } else if (m < 8) {
            int q = m - 4;
            const float* M = w1 + L*4096;
            o[2048 + q*1024 + i] = pkh(M[w*128 + 32*q + c], M[(w+16)*128 + 32*q + c]);
        } else {
            int q = m - 8;
            const float* M = w2 + L*4096;
            o[2048 + q*1024 + 512 + i] = pkh(M[(32*q+w)*32 + c], M[(32*q+16+w)*32 + c]);
        }
    }
}

// w=3 spill-free. LDS-pipe bound: this round cuts write-issue count 4x via
// operand-swapped MFMA (dur tracks LDS op count -- R16/R17/R18 evidence).
__global__ __launch_bounds__(THREADS, 3)
void tf_mfma(const int* __restrict__ toks, const float* __restrict__ temb,
             const float* __restrict__ pemb, const unsigned int* __restrict__ ws,
             float* __restrict__ out, int nelem)
{
    __shared__ unsigned int S[SMEM_U32];
    const int tid  = threadIdx.x;
    const int lane = tid & 63;
    const int wid  = tid >> 6;
    const int llo  = lane & 15, lhi = lane >> 4;
    const int boff = 4 * lhi;
    int le = lane / 6;
    int s  = lane - le * 6;
    if (le > 9) { le = 9; s = 5; }                   // 4 dup lanes/wave (in-bounds)
    const int rb   = wid*64 + le*6;                  // element's slot base (in-wave)
    const int myk  = (tid >> 1) & 3;
    const int elem = blockIdx.x * ELB + wid*10 + le;
    const f32x4 zz = {0.f, 0.f, 0.f, 0.f};

    // tile-output row (act row) and its b128 write/read offset -- shared by ALL
    // MFMA sites (writes now land at the A-frag addresses; content == R16).
    int tOff[4];
    #pragma unroll
    for (int j = 0; j < 4; ++j) {
        int rowa = wid*64 + j*16 + llo;
        tOff[j] = rowa*16 + swg(rowa, lhi);
    }

    h2 X2[16];                                       // residual stream, packed f16 sigma pairs
    {
        const int ti  = (elem < nelem) ? (elem*SEQ + s) : 0;
        const int tok = toks[ti];
        #pragma unroll
        for (int g = 0; g < 4; ++g) {
            float4 alo = *(const float4*)&temb[tok*32 + 4*g];
            float4 ahi = *(const float4*)&temb[tok*32 + 16 + 4*g];
            float4 plo = *(const float4*)&pemb[s*32 + 4*g];
            float4 phi = *(const float4*)&pemb[s*32 + 16 + 4*g];
            X2[4*g+0] = __builtin_bit_cast(h2, pkh(alo.x + plo.x, ahi.x + phi.x));
            X2[4*g+1] = __builtin_bit_cast(h2, pkh(alo.y + plo.y, ahi.y + phi.y));
            X2[4*g+2] = __builtin_bit_cast(h2, pkh(alo.z + plo.z, ahi.z + phi.z));
            X2[4*g+3] = __builtin_bit_cast(h2, pkh(alo.w + plo.w, ahi.w + phi.w));
        }
    }

    #pragma unroll 1
    for (int L = 0; L < NL; ++L) {
        const unsigned int* wsL = ws + L * 6144;

        ln_write(X2, &S[XN], tid);                   // Xn (own slot)

        // ---- QKV: D = W_frag . Act_frag (swapped) -> one b128 write per tile ----
        uint4 q4[4];
        {
            h8 bq0 = ldh(wsL +          llo    *16 + boff);
            h8 bq1 = ldh(wsL +         (llo+16)*16 + boff);
            h8 bk0 = ldh(wsL +  512 +   llo    *16 + boff);
            h8 bk1 = ldh(wsL +  512 +  (llo+16)*16 + boff);
            h8 bv0 = ldh(wsL + 1024 +   llo    *16 + boff);
            h8 bv1 = ldh(wsL + 1024 +  (llo+16)*16 + boff);
            h8 aa[4];
            #pragma unroll
            for (int j = 0; j < 4; ++j) aa[j] = ldh(&S[XN + tOff[j]]);
            #pragma unroll
            for (int j = 0; j < 4; ++j) {            // K -> KP (b128)
                f32x4 k0 = __builtin_amdgcn_mfma_f32_16x16x32_f16(bk0, aa[j], zz, 0,0,0);
                f32x4 k1 = __builtin_amdgcn_mfma_f32_16x16x32_f16(bk1, aa[j], zz, 0,0,0);
                uint4 w;
                w.x = pkh(k0[0], k1[0]); w.y = pkh(k0[1], k1[1]);
                w.z = pkh(k0[2], k1[2]); w.w = pkh(k0[3], k1[3]);
                *(uint4*)&S[KP + tOff[j]] = w;
            }
            #pragma unroll
            for (int j = 0; j < 4; ++j) {            // Q -> XN (over Xn; aa read done)
                f32x4 qa = __builtin_amdgcn_mfma_f32_16x16x32_f16(bq0, aa[j], zz, 0,0,0);
                f32x4 qb = __builtin_amdgcn_mfma_f32_16x16x32_f16(bq1, aa[j], zz, 0,0,0);
                uint4 w;
                w.x = pkh(qa[0], qb[0]); w.y = pkh(qa[1], qb[1]);
                w.z = pkh(qa[2], qb[2]); w.w = pkh(qa[3], qb[3]);
                *(uint4*)&S[XN + tOff[j]] = w;
            }
            #pragma unroll
            for (int h = 0; h < 4; ++h)              // own-row Q (in-wave RAW, in-order DS)
                q4[h] = *(const uint4*)&S[XN + tid*16 + ((h ^ myk) << 2)];
            #pragma unroll
            for (int j = 0; j < 4; ++j) {            // V -> XN (over Q; q4 reads issued)
                f32x4 v0 = __builtin_amdgcn_mfma_f32_16x16x32_f16(bv0, aa[j], zz, 0,0,0);
                f32x4 v1 = __builtin_amdgcn_mfma_f32_16x16x32_f16(bv1, aa[j], zz, 0,0,0);
                uint4 w;
                w.x = pkh(v0[0], v1[0]); w.y = pkh(v0[1], v1[1]);
                w.z = pkh(v0[2], v1[2]); w.w = pkh(v0[3], v1[3]);
                *(uint4*)&S[XN + tOff[j]] = w;
            }
        }

        // ---- attention: ONLINE scores+PV in one pass ----
        // exp2 with folded scale: 0.35355339*log2(e) = 0.51006975. exp2(-1e30)=0 masks.
        {
            float den[4] = {0.f, 0.f, 0.f, 0.f};
            h2 O[16];
            #pragma unroll
            for (int w = 0; w < 16; ++w) O[w] = __builtin_bit_cast(h2, 0u);
            #pragma unroll
            for (int t = 0; t < SEQ; ++t) {
                int krow = rb + t;
                const unsigned int* kr = &S[KP + krow*16];
                const unsigned int* vr = &S[XN + krow*16];
                int kk4 = (krow >> 1) & 3;
                float msk = (t <= s) ? 0.f : -1e30f;
                #pragma unroll
                for (int h = 0; h < 4; ++h) {
                    uint4 kk = *(const uint4*)&kr[(h ^ kk4) << 2];
                    float d = dot2acc(q4[h].x, kk.x, 0.f);
                    d = dot2acc(q4[h].y, kk.y, d);
                    d = dot2acc(q4[h].z, kk.z, d);
                    d = dot2acc(q4[h].w, kk.w, d);
                    float e = exp2f(fmaf(d, 0.51006975f, msk));
                    den[h] += e;
                    h2 wg2 = __builtin_bit_cast(h2, pkh(e, e));
                    uint4 vv = *(const uint4*)&vr[(h ^ kk4) << 2];
                    O[4*h+0] += __builtin_bit_cast(h2, vv.x) * wg2;
                    O[4*h+1] += __builtin_bit_cast(h2, vv.y) * wg2;
                    O[4*h+2] += __builtin_bit_cast(h2, vv.z) * wg2;
                    O[4*h+3] += __builtin_bit_cast(h2, vv.w) * wg2;
                }
            }
            #pragma unroll
            for (int h = 0; h < 4; ++h) {            // normalize
                float rdh = __builtin_amdgcn_rcpf(den[h]);
                h2 rr = __builtin_bit_cast(h2, pkh(rdh, rdh));
                O[4*h+0] *= rr; O[4*h+1] *= rr; O[4*h+2] *= rr; O[4*h+3] *= rr;
            }
            #pragma unroll
            for (int g = 0; g < 4; ++g) {            // O -> KP own slot (over K; reads done)
                uint4 w;
                w.x = __builtin_bit_cast(unsigned int, O[4*g+0]);
                w.y = __builtin_bit_cast(unsigned int, O[4*g+1]);
                w.z = __builtin_bit_cast(unsigned int, O[4*g+2]);
                w.w = __builtin_bit_cast(unsigned int, O[4*g+3]);
                *(uint4*)&S[KP + tid*16 + ((g ^ myk) << 2)] = w;
            }
        }

        // ---- O.Wo (swapped): A=KP(O) frags -> D b128 into XN (over V) ----
        {
            h8 bo0 = ldh(wsL + 1536 +  llo    *16 + boff);
            h8 bo1 = ldh(wsL + 1536 + (llo+16)*16 + boff);
            #pragma unroll
            for (int j = 0; j < 4; ++j) {
                h8 a = ldh(&S[KP + tOff[j]]);
                f32x4 o0 = __builtin_amdgcn_mfma_f32_16x16x32_f16(bo0, a, zz, 0,0,0);
                f32x4 o1 = __builtin_amdgcn_mfma_f32_16x16x32_f16(bo1, a, zz, 0,0,0);
                uint4 w;
                w.x = pkh(o0[0], o1[0]); w.y = pkh(o0[1], o1[1]);
                w.z = pkh(o0[2], o1[2]); w.w = pkh(o0[3], o1[3]);
                *(uint4*)&S[XN + tOff[j]] = w;
            }
        }
        #pragma unroll
        for (int g = 0; g < 4; ++g) {                // residual (own slot, packed adds)
            uint4 v = *(const uint4*)&S[XN + tid*16 + ((g ^ myk) << 2)];
            X2[4*g+0] += __builtin_bit_cast(h2, v.x);
            X2[4*g+1] += __builtin_bit_cast(h2, v.y);
            X2[4*g+2] += __builtin_bit_cast(h2, v.z);
            X2[4*g+3] += __builtin_bit_cast(h2, v.w);
        }
        ln_write(X2, &S[KP], tid);                   // Xn2 -> KP (over O; A reads issued)

        // ---- FFN: Xn2 A-frags hoisted (read once); H/FFN2 writes are b128 ----
        h8 aa2[4];
        #pragma unroll
        for (int j = 0; j < 4; ++j) aa2[j] = ldh(&S[KP + tOff[j]]);
        f32x4 cf[4][2];
        #pragma unroll
        for (int j = 0; j < 4; ++j) { cf[j][0] = zz; cf[j][1] = zz; }
        #pragma unroll
        for (int q = 0; q < 4; ++q) {
            const unsigned int* wq4 = wsL + 2048 + q*1024;
            h8 b10 = ldh(wq4 +        llo    *16 + boff);
            h8 b11 = ldh(wq4 +       (llo+16)*16 + boff);
            h8 b20 = ldh(wq4 + 512 +  llo    *16 + boff);
            h8 b21 = ldh(wq4 + 512 + (llo+16)*16 + boff);
            #pragma unroll
            for (int j = 0; j < 4; ++j) {            // H (GELU) -> XN, b128
                f32x4 h0 = __builtin_amdgcn_mfma_f32_16x16x32_f16(b10, aa2[j], zz, 0,0,0);
                f32x4 h1 = __builtin_amdgcn_mfma_f32_16x16x32_f16(b11, aa2[j], zz, 0,0,0);
                uint4 w;
                w.x = gelu2(h0[0], h1[0]); w.y = gelu2(h0[1], h1[1]);
                w.z = gelu2(h0[2], h1[2]); w.w = gelu2(h0[3], h1[3]);
                *(uint4*)&S[XN + tOff[j]] = w;
            }
            #pragma unroll
            for (int j = 0; j < 4; ++j) {            // FFN2 (H rows in-wave)
                h8 ah = ldh(&S[XN + tOff[j]]);
                cf[j][0] = __builtin_amdgcn_mfma_f32_16x16x32_f16(b20, ah, cf[j][0], 0,0,0);
                cf[j][1] = __builtin_amdgcn_mfma_f32_16x16x32_f16(b21, ah, cf[j][1], 0,0,0);
            }
        }
        #pragma unroll
        for (int j = 0; j < 4; ++j) {                // FFN2 out -> XN (over H), b128
            uint4 w;
            w.x = pkh(cf[j][0][0], cf[j][1][0]); w.y = pkh(cf[j][0][1], cf[j][1][1]);
            w.z = pkh(cf[j][0][2], cf[j][1][2]); w.w = pkh(cf[j][0][3], cf[j][1][3]);
            *(uint4*)&S[XN + tOff[j]] = w;
        }
        #pragma unroll
        for (int g = 0; g < 4; ++g) {                // residual (own slot, packed adds)
            uint4 v = *(const uint4*)&S[XN + tid*16 + ((g ^ myk) << 2)];
            X2[4*g+0] += __builtin_bit_cast(h2, v.x);
            X2[4*g+1] += __builtin_bit_cast(h2, v.y);
            X2[4*g+2] += __builtin_bit_cast(h2, v.z);
            X2[4*g+3] += __builtin_bit_cast(h2, v.w);
        }
    }

    // ---- final LN + weight-tied logits (swapped; one b128 f32 write per j) ----
    ln_write(X2, &S[XN], tid);
    {
        h8 bt = ldh(ws + 12288 + llo*16 + boff);
        #pragma unroll
        for (int j = 0; j < 4; ++j) {
            h8 a = ldh(&S[XN + tOff[j]]);
            f32x4 lg = __builtin_amdgcn_mfma_f32_16x16x32_f16(bt, a, zz, 0,0,0);
            uint4 w;
            w.x = __float_as_uint(lg[0]); w.y = __float_as_uint(lg[1]);
            w.z = __float_as_uint(lg[2]); w.w = __float_as_uint(lg[3]);
            *(uint4*)&S[KP + tOff[j]] = w;           // word idx = vocab idx (as before)
        }
    }
    __syncthreads();                                 // the only barrier
    {
        const long long obase = (long long)blockIdx.x * (ELB*SEQ*VOC);   // 3600
        const long long tot   = (long long)nelem * (SEQ*VOC);
        for (int i = tid; i < ELB*SEQ*VOC; i += THREADS) {
            if (obase + i < tot) {
                int rl   = i / VOC, col = i - rl*VOC;
                int w    = rl / 60, r6 = rl - w*60;
                int slot = w*64 + r6;
                out[obase + i] = __uint_as_float(
                    S[KP + slot*16 + (((col >> 2) ^ ((slot >> 1) & 3)) << 2) + (col & 3)]);
            }
        }
    }
}

extern "C" void kernel_launch(void* const* d_in, const int* in_sizes, int n_in,
                              void* d_out, int out_size, void* d_ws, size_t ws_size,
                              hipStream_t stream) {
    const int*   toks = (const int*)  d_in[0];
    const float* temb = (const float*)d_in[1];
    const float* pemb = (const float*)d_in[2];
    const float* wq   = (const float*)d_in[3];
    const float* wk   = (const float*)d_in[4];
    const float* wv   = (const float*)d_in[5];
    const float* wo   = (const float*)d_in[6];
    const float* w1   = (const float*)d_in[7];
    const float* w2   = (const float*)d_in[8];
    unsigned int* ws  = (unsigned int*)d_ws;         // 12544 u32 = 50 KB used
    float* out = (float*)d_out;
    const int nelem = in_sizes[0] / SEQ;             // 131072
    const int nblk  = (nelem + ELB - 1) / ELB;       // 3277

    prep<<<dim3(25), dim3(64), 0, stream>>>(temb, wq, wk, wv, wo, w1, w2, ws);
    tf_mfma<<<dim3(nblk), dim3(THREADS), 0, stream>>>(toks, temb, pemb, ws, out, nelem);
}

// Round 20
// 130.056 us; speedup vs baseline: 1.0901x; 1.0197x over previous
//
#include <hip/hip_runtime.h>

#define SEQ 6
#define THREADS 256              // 4 waves; 10 elements per wave (60 active lanes)
#define ELB 40                   // elements per block
#define NL 2
#define VOC 15

typedef __attribute__((ext_vector_type(8))) _Float16 h8;
typedef __attribute__((ext_vector_type(2))) _Float16 h2;
typedef __attribute__((ext_vector_type(4))) float    f32x4;

// LDS: 2 pools x 256 slots x 16 u32, XOR-swizzled 16B groups. 8192 u32 = 32 KB.
// Swapped-MFMA layout (R19): lane llo holds 4 consecutive sigma-words of act
// row llo -> tile outputs are single b128 writes at the A-frag address.
// NEW (R20): H never touches LDS at all -- the H-MFMA output fragment in a lane
// is EXACTLY the FFN2 B-operand fragment for the same lane (write addr == read
// addr == same lane in R19), so we bit_cast the gelu2-packed words straight
// into the next MFMA. Deletes 32 b128 ops/thread/layer (~24% of LDS traffic).
#define XN 0          // Xn -> Q -> V -> OWo -> FFN2
#define KP 4096       // K -> O -> Xn2 -> logits f32
#define SMEM_U32 8192

// ws layout (u32): per layer L at L*6144: Wq 0, Wk 512, Wv 1024, Wo 1536,
// quarter q: 2048+q*1024 (W1q at +0, W2q at +512). TE at 12288 (256).

__device__ __forceinline__ unsigned int pkh(float a, float b) {
    auto h = __builtin_amdgcn_cvt_pkrtz(a, b);
    return __builtin_bit_cast(unsigned int, h);
}
__device__ __forceinline__ h8 ldh(const unsigned int* p) {
    uint4 u = *(const uint4*)p;
    return __builtin_bit_cast(h8, u);
}
#if __has_builtin(__builtin_amdgcn_fdot2)
__device__ __forceinline__ float dot2acc(unsigned int a, unsigned int b, float c) {
    return __builtin_amdgcn_fdot2(__builtin_bit_cast(h2, a), __builtin_bit_cast(h2, b), c, false);
}
__device__ __forceinline__ float dot2h(h2 a, h2 b, float c) {
    return __builtin_amdgcn_fdot2(a, b, c, false);
}
#else
__device__ __forceinline__ float dot2acc(unsigned int a, unsigned int b, float c) {
    h2 ha = __builtin_bit_cast(h2, a), hb = __builtin_bit_cast(h2, b);
    return fmaf((float)ha.y, (float)hb.y, fmaf((float)ha.x, (float)hb.x, c));
}
__device__ __forceinline__ float dot2h(h2 a, h2 b, float c) {
    return fmaf((float)a.y, (float)b.y, fmaf((float)a.x, (float)b.x, c));
}
#endif
#define H2C(v) ((h2){(_Float16)(v), (_Float16)(v)})
// GELU on a PAIR in packed f16 (v_pk_* ops). Odd-poly fit of erf(x/sqrt2),
// |x|<=3, |err|<=3e-3 f32 + <=4e-3 f16 Horner. Result ready as packed word.
__device__ __forceinline__ unsigned int gelu2(float a, float b) {
    h2 xp = __builtin_bit_cast(h2, pkh(a, b));
#if __has_builtin(__builtin_elementwise_max) && __has_builtin(__builtin_elementwise_min)
    h2 xc = __builtin_elementwise_min(__builtin_elementwise_max(xp, H2C(-3.0f)), H2C(3.0f));
#else
    h2 xc = __builtin_bit_cast(h2, pkh(fminf(fmaxf(a, -3.0f), 3.0f),
                                       fminf(fmaxf(b, -3.0f), 3.0f)));
#endif
    h2 u = xc * xc;
    h2 p = H2C(4.80757e-5f);
    p = p * u + H2C(-1.40632e-3f);
    p = p * u + H2C(1.75795e-2f);
    p = p * u + H2C(-1.30947e-1f);
    p = p * u + H2C(7.9714e-1f);
    h2 hx = xp * H2C(0.5f);
    h2 r  = (hx * xc) * p + hx;                  // 0.5x(1 + xc*P(u))
    return __builtin_bit_cast(unsigned int, r);
}
__device__ __forceinline__ int permc(int p) {        // head-local sigma pairs
    int h = (p & 15) >> 2, j = p & 3, hi = p >> 4;
    return 8*h + 2*j + hi;
}
__device__ __forceinline__ int swg(int row, int g) { // swizzled 16B-group offset
    return ((g ^ ((row >> 1) & 3)) << 2);
}
// LN over the packed-f16 residual X2[16] (sigma pairs: word w = cols (w, w+16)).
__device__ __forceinline__ void ln_write(const h2* X2, unsigned int* base, int row) {
    const h2 one = H2C(1.0f);
    float mu = 0.f;
    #pragma unroll
    for (int w = 0; w < 16; ++w) mu = dot2h(X2[w], one, mu);
    mu *= 0.03125f;
    h2 mu2 = __builtin_bit_cast(h2, pkh(mu, mu));
    float var = 0.f;
    #pragma unroll
    for (int w = 0; w < 16; ++w) { h2 d = X2[w] - mu2; var = dot2h(d, d, var); }
    var *= 0.03125f;
    float rs = rsqrtf(var + 1e-5f), b = -mu * rs;
    h2 rs2 = __builtin_bit_cast(h2, pkh(rs, rs));
    h2 b2  = __builtin_bit_cast(h2, pkh(b, b));
    unsigned int* rp = base + row * 16;
    const int k = (row >> 1) & 3;
    #pragma unroll
    for (int g = 0; g < 4; ++g) {
        uint4 w;
        w.x = __builtin_bit_cast(unsigned int, X2[4*g+0] * rs2 + b2);
        w.y = __builtin_bit_cast(unsigned int, X2[4*g+1] * rs2 + b2);
        w.z = __builtin_bit_cast(unsigned int, X2[4*g+2] * rs2 + b2);
        w.w = __builtin_bit_cast(unsigned int, X2[4*g+3] * rs2 + b2);
        *(uint4*)&rp[(g ^ k) << 2] = w;
    }
}

// ---- prep: pre-pack all weights (f16, transposed, head-permuted) into ws ----
__global__ __launch_bounds__(64) void prep(
    const float* __restrict__ temb, const float* __restrict__ wq,
    const float* __restrict__ wk, const float* __restrict__ wv,
    const float* __restrict__ wo, const float* __restrict__ w1,
    const float* __restrict__ w2, unsigned int* __restrict__ ws)
{
    const int part = blockIdx.x;          // 0..24
    const int t = threadIdx.x;
    if (part == 24) {                     // TE tile
        for (int i = t; i < 256; i += 64) {
            int c = i >> 4, w = i & 15;
            ws[12288 + i] = (c < VOC) ? pkh(temb[c*32 + w], temb[c*32 + w + 16]) : 0u;
        }
        return;
    }
    const int L = part / 12, m = part % 12;
    unsigned int* o = ws + L * 6144;
    for (int i = t; i < 512; i += 64) {
        int c = i >> 4, w = i & 15;
        if (m < 3) {
            const float* M = (m == 0 ? wq : (m == 1 ? wk : wv)) + L*1024;
            int pc = permc(c);
            o[m*512 + i] = pkh(M[w*32 + pc], M[(w+16)*32 + pc]);
        } else if (m == 3) {
            const float* M = wo + L*1024;
            o[1536 + i] = pkh(M[permc(w)*32 + c], M[permc(w+16)*32 + c]);
        } else if (m < 8) {
            int q = m - 4;
            const float* M = w1 + L*4096;
            o[2048 + q*1024 + i] = pkh(M[w*128 + 32*q + c], M[(w+16)*128 + 32*q + c]);
        } else {
            int q = m - 8;
            const float* M = w2 + L*4096;
            o[2048 + q*1024 + 512 + i] = pkh(M[(32*q+w)*32 + c], M[(32*q+16+w)*32 + c]);
        }
    }
}

// w=3 spill-free. LDS-pipe bound; this round deletes the H round-trip (the
// fragment-layout identity makes it a no-op) -- dur tracks LDS op count.
__global__ __launch_bounds__(THREADS, 3)
void tf_mfma(const int* __restrict__ toks, const float* __restrict__ temb,
             const float* __restrict__ pemb, const unsigned int* __restrict__ ws,
             float* __restrict__ out, int nelem)
{
    __shared__ unsigned int S[SMEM_U32];
    const int tid  = threadIdx.x;
    const int lane = tid & 63;
    const int wid  = tid >> 6;
    const int llo  = lane & 15, lhi = lane >> 4;
    const int boff = 4 * lhi;
    int le = lane / 6;
    int s  = lane - le * 6;
    if (le > 9) { le = 9; s = 5; }                   // 4 dup lanes/wave (in-bounds)
    const int rb   = wid*64 + le*6;                  // element's slot base (in-wave)
    const int myk  = (tid >> 1) & 3;
    const int elem = blockIdx.x * ELB + wid*10 + le;
    const f32x4 zz = {0.f, 0.f, 0.f, 0.f};

    // tile-output row (act row) offset, shared by all MFMA sites
    int tOff[4];
    #pragma unroll
    for (int j = 0; j < 4; ++j) {
        int rowa = wid*64 + j*16 + llo;
        tOff[j] = rowa*16 + swg(rowa, lhi);
    }

    h2 X2[16];                                       // residual stream, packed f16 sigma pairs
    {
        const int ti  = (elem < nelem) ? (elem*SEQ + s) : 0;
        const int tok = toks[ti];
        #pragma unroll
        for (int g = 0; g < 4; ++g) {
            float4 alo = *(const float4*)&temb[tok*32 + 4*g];
            float4 ahi = *(const float4*)&temb[tok*32 + 16 + 4*g];
            float4 plo = *(const float4*)&pemb[s*32 + 4*g];
            float4 phi = *(const float4*)&pemb[s*32 + 16 + 4*g];
            X2[4*g+0] = __builtin_bit_cast(h2, pkh(alo.x + plo.x, ahi.x + phi.x));
            X2[4*g+1] = __builtin_bit_cast(h2, pkh(alo.y + plo.y, ahi.y + phi.y));
            X2[4*g+2] = __builtin_bit_cast(h2, pkh(alo.z + plo.z, ahi.z + phi.z));
            X2[4*g+3] = __builtin_bit_cast(h2, pkh(alo.w + plo.w, ahi.w + phi.w));
        }
    }

    #pragma unroll 1
    for (int L = 0; L < NL; ++L) {
        const unsigned int* wsL = ws + L * 6144;

        ln_write(X2, &S[XN], tid);                   // Xn (own slot)

        // ---- QKV: D = W_frag . Act_frag (swapped) -> one b128 write per tile ----
        uint4 q4[4];
        {
            h8 bq0 = ldh(wsL +          llo    *16 + boff);
            h8 bq1 = ldh(wsL +         (llo+16)*16 + boff);
            h8 bk0 = ldh(wsL +  512 +   llo    *16 + boff);
            h8 bk1 = ldh(wsL +  512 +  (llo+16)*16 + boff);
            h8 bv0 = ldh(wsL + 1024 +   llo    *16 + boff);
            h8 bv1 = ldh(wsL + 1024 +  (llo+16)*16 + boff);
            h8 aa[4];
            #pragma unroll
            for (int j = 0; j < 4; ++j) aa[j] = ldh(&S[XN + tOff[j]]);
            #pragma unroll
            for (int j = 0; j < 4; ++j) {            // K -> KP (b128)
                f32x4 k0 = __builtin_amdgcn_mfma_f32_16x16x32_f16(bk0, aa[j], zz, 0,0,0);
                f32x4 k1 = __builtin_amdgcn_mfma_f32_16x16x32_f16(bk1, aa[j], zz, 0,0,0);
                uint4 w;
                w.x = pkh(k0[0], k1[0]); w.y = pkh(k0[1], k1[1]);
                w.z = pkh(k0[2], k1[2]); w.w = pkh(k0[3], k1[3]);
                *(uint4*)&S[KP + tOff[j]] = w;
            }
            #pragma unroll
            for (int j = 0; j < 4; ++j) {            // Q -> XN (over Xn; aa read done)
                f32x4 qa = __builtin_amdgcn_mfma_f32_16x16x32_f16(bq0, aa[j], zz, 0,0,0);
                f32x4 qb = __builtin_amdgcn_mfma_f32_16x16x32_f16(bq1, aa[j], zz, 0,0,0);
                uint4 w;
                w.x = pkh(qa[0], qb[0]); w.y = pkh(qa[1], qb[1]);
                w.z = pkh(qa[2], qb[2]); w.w = pkh(qa[3], qb[3]);
                *(uint4*)&S[XN + tOff[j]] = w;
            }
            #pragma unroll
            for (int h = 0; h < 4; ++h)              // own-row Q (in-wave RAW, in-order DS)
                q4[h] = *(const uint4*)&S[XN + tid*16 + ((h ^ myk) << 2)];
            #pragma unroll
            for (int j = 0; j < 4; ++j) {            // V -> XN (over Q; q4 reads issued)
                f32x4 v0 = __builtin_amdgcn_mfma_f32_16x16x32_f16(bv0, aa[j], zz, 0,0,0);
                f32x4 v1 = __builtin_amdgcn_mfma_f32_16x16x32_f16(bv1, aa[j], zz, 0,0,0);
                uint4 w;
                w.x = pkh(v0[0], v1[0]); w.y = pkh(v0[1], v1[1]);
                w.z = pkh(v0[2], v1[2]); w.w = pkh(v0[3], v1[3]);
                *(uint4*)&S[XN + tOff[j]] = w;
            }
        }

        // ---- attention: ONLINE scores+PV in one pass ----
        // exp2 with folded scale: 0.35355339*log2(e) = 0.51006975. exp2(-1e30)=0 masks.
        {
            float den[4] = {0.f, 0.f, 0.f, 0.f};
            h2 O[16];
            #pragma unroll
            for (int w = 0; w < 16; ++w) O[w] = __builtin_bit_cast(h2, 0u);
            #pragma unroll
            for (int t = 0; t < SEQ; ++t) {
                int krow = rb + t;
                const unsigned int* kr = &S[KP + krow*16];
                const unsigned int* vr = &S[XN + krow*16];
                int kk4 = (krow >> 1) & 3;
                float msk = (t <= s) ? 0.f : -1e30f;
                #pragma unroll
                for (int h = 0; h < 4; ++h) {
                    uint4 kk = *(const uint4*)&kr[(h ^ kk4) << 2];
                    float d = dot2acc(q4[h].x, kk.x, 0.f);
                    d = dot2acc(q4[h].y, kk.y, d);
                    d = dot2acc(q4[h].z, kk.z, d);
                    d = dot2acc(q4[h].w, kk.w, d);
                    float e = exp2f(fmaf(d, 0.51006975f, msk));
                    den[h] += e;
                    h2 wg2 = __builtin_bit_cast(h2, pkh(e, e));
                    uint4 vv = *(const uint4*)&vr[(h ^ kk4) << 2];
                    O[4*h+0] += __builtin_bit_cast(h2, vv.x) * wg2;
                    O[4*h+1] += __builtin_bit_cast(h2, vv.y) * wg2;
                    O[4*h+2] += __builtin_bit_cast(h2, vv.z) * wg2;
                    O[4*h+3] += __builtin_bit_cast(h2, vv.w) * wg2;
                }
            }
            #pragma unroll
            for (int h = 0; h < 4; ++h) {            // normalize
                float rdh = __builtin_amdgcn_rcpf(den[h]);
                h2 rr = __builtin_bit_cast(h2, pkh(rdh, rdh));
                O[4*h+0] *= rr; O[4*h+1] *= rr; O[4*h+2] *= rr; O[4*h+3] *= rr;
            }
            #pragma unroll
            for (int g = 0; g < 4; ++g) {            // O -> KP own slot (over K; reads done)
                uint4 w;
                w.x = __builtin_bit_cast(unsigned int, O[4*g+0]);
                w.y = __builtin_bit_cast(unsigned int, O[4*g+1]);
                w.z = __builtin_bit_cast(unsigned int, O[4*g+2]);
                w.w = __builtin_bit_cast(unsigned int, O[4*g+3]);
                *(uint4*)&S[KP + tid*16 + ((g ^ myk) << 2)] = w;
            }
        }

        // ---- O.Wo (swapped): A=KP(O) frags -> D b128 into XN (over V) ----
        {
            h8 bo0 = ldh(wsL + 1536 +  llo    *16 + boff);
            h8 bo1 = ldh(wsL + 1536 + (llo+16)*16 + boff);
            #pragma unroll
            for (int j = 0; j < 4; ++j) {
                h8 a = ldh(&S[KP + tOff[j]]);
                f32x4 o0 = __builtin_amdgcn_mfma_f32_16x16x32_f16(bo0, a, zz, 0,0,0);
                f32x4 o1 = __builtin_amdgcn_mfma_f32_16x16x32_f16(bo1, a, zz, 0,0,0);
                uint4 w;
                w.x = pkh(o0[0], o1[0]); w.y = pkh(o0[1], o1[1]);
                w.z = pkh(o0[2], o1[2]); w.w = pkh(o0[3], o1[3]);
                *(uint4*)&S[XN + tOff[j]] = w;
            }
        }
        #pragma unroll
        for (int g = 0; g < 4; ++g) {                // residual (own slot, packed adds)
            uint4 v = *(const uint4*)&S[XN + tid*16 + ((g ^ myk) << 2)];
            X2[4*g+0] += __builtin_bit_cast(h2, v.x);
            X2[4*g+1] += __builtin_bit_cast(h2, v.y);
            X2[4*g+2] += __builtin_bit_cast(h2, v.z);
            X2[4*g+3] += __builtin_bit_cast(h2, v.w);
        }
        ln_write(X2, &S[KP], tid);                   // Xn2 -> KP (over O; A reads issued)

        // ---- FFN: Xn2 A-frags read once; H stays ENTIRELY in registers:
        // the H-MFMA output fragment (after gelu2 pack) IS the FFN2 B-operand
        // fragment for this lane (write addr == read addr in R19) -> bit_cast.
        h8 aa2[4];
        #pragma unroll
        for (int j = 0; j < 4; ++j) aa2[j] = ldh(&S[KP + tOff[j]]);
        f32x4 cf[4][2];
        #pragma unroll
        for (int j = 0; j < 4; ++j) { cf[j][0] = zz; cf[j][1] = zz; }
        #pragma unroll
        for (int q = 0; q < 4; ++q) {
            const unsigned int* wq4 = wsL + 2048 + q*1024;
            h8 b10 = ldh(wq4 +        llo    *16 + boff);
            h8 b11 = ldh(wq4 +       (llo+16)*16 + boff);
            h8 b20 = ldh(wq4 + 512 +  llo    *16 + boff);
            h8 b21 = ldh(wq4 + 512 + (llo+16)*16 + boff);
            #pragma unroll
            for (int j = 0; j < 4; ++j) {
                f32x4 h0 = __builtin_amdgcn_mfma_f32_16x16x32_f16(b10, aa2[j], zz, 0,0,0);
                f32x4 h1 = __builtin_amdgcn_mfma_f32_16x16x32_f16(b11, aa2[j], zz, 0,0,0);
                uint4 w;
                w.x = gelu2(h0[0], h1[0]); w.y = gelu2(h0[1], h1[1]);
                w.z = gelu2(h0[2], h1[2]); w.w = gelu2(h0[3], h1[3]);
                h8 ah = __builtin_bit_cast(h8, w);   // fragment identity: no LDS
                cf[j][0] = __builtin_amdgcn_mfma_f32_16x16x32_f16(b20, ah, cf[j][0], 0,0,0);
                cf[j][1] = __builtin_amdgcn_mfma_f32_16x16x32_f16(b21, ah, cf[j][1], 0,0,0);
            }
        }
        #pragma unroll
        for (int j = 0; j < 4; ++j) {                // FFN2 out -> XN, b128
            uint4 w;
            w.x = pkh(cf[j][0][0], cf[j][1][0]); w.y = pkh(cf[j][0][1], cf[j][1][1]);
            w.z = pkh(cf[j][0][2], cf[j][1][2]); w.w = pkh(cf[j][0][3], cf[j][1][3]);
            *(uint4*)&S[XN + tOff[j]] = w;
        }
        #pragma unroll
        for (int g = 0; g < 4; ++g) {                // residual (own slot, packed adds)
            uint4 v = *(const uint4*)&S[XN + tid*16 + ((g ^ myk) << 2)];
            X2[4*g+0] += __builtin_bit_cast(h2, v.x);
            X2[4*g+1] += __builtin_bit_cast(h2, v.y);
            X2[4*g+2] += __builtin_bit_cast(h2, v.z);
            X2[4*g+3] += __builtin_bit_cast(h2, v.w);
        }
    }

    // ---- final LN + weight-tied logits (swapped; one b128 f32 write per j) ----
    ln_write(X2, &S[XN], tid);
    {
        h8 bt = ldh(ws + 12288 + llo*16 + boff);
        #pragma unroll
        for (int j = 0; j < 4; ++j) {
            h8 a = ldh(&S[XN + tOff[j]]);
            f32x4 lg = __builtin_amdgcn_mfma_f32_16x16x32_f16(bt, a, zz, 0,0,0);
            uint4 w;
            w.x = __float_as_uint(lg[0]); w.y = __float_as_uint(lg[1]);
            w.z = __float_as_uint(lg[2]); w.w = __float_as_uint(lg[3]);
            *(uint4*)&S[KP + tOff[j]] = w;           // word idx = vocab idx (as before)
        }
    }
    __syncthreads();                                 // the only barrier
    {
        const long long obase = (long long)blockIdx.x * (ELB*SEQ*VOC);   // 3600
        const long long tot   = (long long)nelem * (SEQ*VOC);
        for (int i = tid; i < ELB*SEQ*VOC; i += THREADS) {
            if (obase + i < tot) {
                int rl   = i / VOC, col = i - rl*VOC;
                int w    = rl / 60, r6 = rl - w*60;
                int slot = w*64 + r6;
                out[obase + i] = __uint_as_float(
                    S[KP + slot*16 + (((col >> 2) ^ ((slot >> 1) & 3)) << 2) + (col & 3)]);
            }
        }
    }
}

extern "C" void kernel_launch(void* const* d_in, const int* in_sizes, int n_in,
                              void* d_out, int out_size, void* d_ws, size_t ws_size,
                              hipStream_t stream) {
    const int*   toks = (const int*)  d_in[0];
    const float* temb = (const float*)d_in[1];
    const float* pemb = (const float*)d_in[2];
    const float* wq   = (const float*)d_in[3];
    const float* wk   = (const float*)d_in[4];
    const float* wv   = (const float*)d_in[5];
    const float* wo   = (const float*)d_in[6];
    const float* w1   = (const float*)d_in[7];
    const float* w2   = (const float*)d_in[8];
    unsigned int* ws  = (unsigned int*)d_ws;         // 12544 u32 = 50 KB used
    float* out = (float*)d_out;
    const int nelem = in_sizes[0] / SEQ;             // 131072
    const int nblk  = (nelem + ELB - 1) / ELB;       // 3277

    prep<<<dim3(25), dim3(64), 0, stream>>>(temb, wq, wk, wv, wo, w1, w2, ws);
    tf_mfma<<<dim3(nblk), dim3(THREADS), 0, stream>>>(toks, temb, pemb, ws, out, nelem);
}

// Round 21
// 128.609 us; speedup vs baseline: 1.1023x; 1.0112x over previous
//
#include <hip/hip_runtime.h>

#define SEQ 6
#define THREADS 256              // 4 waves; 10 elements per wave (60 active lanes)
#define ELB 40                   // elements per block
#define NL 2
#define VOC 15

typedef __attribute__((ext_vector_type(8))) _Float16 h8;
typedef __attribute__((ext_vector_type(2))) _Float16 h2;
typedef __attribute__((ext_vector_type(4))) float    f32x4;

// LDS: 2 pools x 256 slots x 16 u32, XOR-swizzled 16B groups. 8192 u32 = 32 KB.
// Swapped-MFMA layout (R19): lane llo holds 4 consecutive sigma-words of act
// row llo -> tile outputs are single b128 writes at the A-frag address.
// H never touches LDS (R20 fragment identity).
#define XN 0          // Xn -> Q -> V -> OWo -> FFN2
#define KP 4096       // K -> O -> Xn2 -> logits f32
#define SMEM_U32 8192

// ws layout (u32): per layer L at L*6144: Wq 0, Wk 512, Wv 1024, Wo 1536,
// quarter q: 2048+q*1024 (W1q at +0, W2q at +512). TE at 12288 (256).

__device__ __forceinline__ unsigned int pkh(float a, float b) {
    auto h = __builtin_amdgcn_cvt_pkrtz(a, b);
    return __builtin_bit_cast(unsigned int, h);
}
__device__ __forceinline__ h8 ldh(const unsigned int* p) {
    uint4 u = *(const uint4*)p;
    return __builtin_bit_cast(h8, u);
}
#if __has_builtin(__builtin_amdgcn_fdot2)
__device__ __forceinline__ float dot2acc(unsigned int a, unsigned int b, float c) {
    return __builtin_amdgcn_fdot2(__builtin_bit_cast(h2, a), __builtin_bit_cast(h2, b), c, false);
}
__device__ __forceinline__ float dot2h(h2 a, h2 b, float c) {
    return __builtin_amdgcn_fdot2(a, b, c, false);
}
#else
__device__ __forceinline__ float dot2acc(unsigned int a, unsigned int b, float c) {
    h2 ha = __builtin_bit_cast(h2, a), hb = __builtin_bit_cast(h2, b);
    return fmaf((float)ha.y, (float)hb.y, fmaf((float)ha.x, (float)hb.x, c));
}
__device__ __forceinline__ float dot2h(h2 a, h2 b, float c) {
    return fmaf((float)a.y, (float)b.y, fmaf((float)a.x, (float)b.x, c));
}
#endif
#define H2C(v) ((h2){(_Float16)(v), (_Float16)(v)})
// GELU on a PAIR in packed f16 (v_pk_* ops). Odd-poly fit of erf(x/sqrt2),
// |x|<=3, |err|<=3e-3 f32 + <=4e-3 f16 Horner. Result ready as packed word.
__device__ __forceinline__ unsigned int gelu2(float a, float b) {
    h2 xp = __builtin_bit_cast(h2, pkh(a, b));
#if __has_builtin(__builtin_elementwise_max) && __has_builtin(__builtin_elementwise_min)
    h2 xc = __builtin_elementwise_min(__builtin_elementwise_max(xp, H2C(-3.0f)), H2C(3.0f));
#else
    h2 xc = __builtin_bit_cast(h2, pkh(fminf(fmaxf(a, -3.0f), 3.0f),
                                       fminf(fmaxf(b, -3.0f), 3.0f)));
#endif
    h2 u = xc * xc;
    h2 p = H2C(4.80757e-5f);
    p = p * u + H2C(-1.40632e-3f);
    p = p * u + H2C(1.75795e-2f);
    p = p * u + H2C(-1.30947e-1f);
    p = p * u + H2C(7.9714e-1f);
    h2 hx = xp * H2C(0.5f);
    h2 r  = (hx * xc) * p + hx;                  // 0.5x(1 + xc*P(u))
    return __builtin_bit_cast(unsigned int, r);
}
__device__ __forceinline__ int permc(int p) {        // head-local sigma pairs
    int h = (p & 15) >> 2, j = p & 3, hi = p >> 4;
    return 8*h + 2*j + hi;
}
__device__ __forceinline__ int swg(int row, int g) { // swizzled 16B-group offset
    return ((g ^ ((row >> 1) & 3)) << 2);
}
// ONE-PASS LN over packed-f16 residual X2[16] (sigma pairs): Sum(x) and Sum(x^2)
// accumulated concurrently in f32 (independent dot2 chains -> better ILP,
// no 16 pk_subs); var = E[x^2] - mu^2.
__device__ __forceinline__ void ln_write(const h2* X2, unsigned int* base, int row) {
    const h2 one = H2C(1.0f);
    float mu = 0.f, sq = 0.f;
    #pragma unroll
    for (int w = 0; w < 16; ++w) {
        mu = dot2h(X2[w], one, mu);
        sq = dot2h(X2[w], X2[w], sq);
    }
    mu *= 0.03125f;
    float var = fmaf(sq, 0.03125f, -mu * mu);
    float rs = rsqrtf(var + 1e-5f), b = -mu * rs;
    h2 rs2 = __builtin_bit_cast(h2, pkh(rs, rs));
    h2 b2  = __builtin_bit_cast(h2, pkh(b, b));
    unsigned int* rp = base + row * 16;
    const int k = (row >> 1) & 3;
    #pragma unroll
    for (int g = 0; g < 4; ++g) {
        uint4 w;
        w.x = __builtin_bit_cast(unsigned int, X2[4*g+0] * rs2 + b2);
        w.y = __builtin_bit_cast(unsigned int, X2[4*g+1] * rs2 + b2);
        w.z = __builtin_bit_cast(unsigned int, X2[4*g+2] * rs2 + b2);
        w.w = __builtin_bit_cast(unsigned int, X2[4*g+3] * rs2 + b2);
        *(uint4*)&rp[(g ^ k) << 2] = w;
    }
}

// ---- prep: pre-pack all weights (f16, transposed, head-permuted) into ws ----
__global__ __launch_bounds__(64) void prep(
    const float* __restrict__ temb, const float* __restrict__ wq,
    const float* __restrict__ wk, const float* __restrict__ wv,
    const float* __restrict__ wo, const float* __restrict__ w1,
    const float* __restrict__ w2, unsigned int* __restrict__ ws)
{
    const int part = blockIdx.x;          // 0..24
    const int t = threadIdx.x;
    if (part == 24) {                     // TE tile
        for (int i = t; i < 256; i += 64) {
            int c = i >> 4, w = i & 15;
            ws[12288 + i] = (c < VOC) ? pkh(temb[c*32 + w], temb[c*32 + w + 16]) : 0u;
        }
        return;
    }
    const int L = part / 12, m = part % 12;
    unsigned int* o = ws + L * 6144;
    for (int i = t; i < 512; i += 64) {
        int c = i >> 4, w = i & 15;
        if (m < 3) {
            const float* M = (m == 0 ? wq : (m == 1 ? wk : wv)) + L*1024;
            int pc = permc(c);
            o[m*512 + i] = pkh(M[w*32 + pc], M[(w+16)*32 + pc]);
        } else if (m == 3) {
            const float* M = wo + L*1024;
            o[1536 + i] = pkh(M[permc(w)*32 + c], M[permc(w+16)*32 + c]);
        } else if (m < 8) {
            int q = m - 4;
            const float* M = w1 + L*4096;
            o[2048 + q*1024 + i] = pkh(M[w*128 + 32*q + c], M[(w+16)*128 + 32*q + c]);
        } else {
            int q = m - 8;
            const float* M = w2 + L*4096;
            o[2048 + q*1024 + 512 + i] = pkh(M[(32*q+w)*32 + c], M[(32*q+16+w)*32 + c]);
        }
    }
}

// w=3 spill-free. Latency/issue-bound plateau: this round removes the last
// provably-positive VALU (one-pass LN, div-free epilogue).
__global__ __launch_bounds__(THREADS, 3)
void tf_mfma(const int* __restrict__ toks, const float* __restrict__ temb,
             const float* __restrict__ pemb, const unsigned int* __restrict__ ws,
             float* __restrict__ out, int nelem)
{
    __shared__ unsigned int S[SMEM_U32];
    const int tid  = threadIdx.x;
    const int lane = tid & 63;
    const int wid  = tid >> 6;
    const int llo  = lane & 15, lhi = lane >> 4;
    const int boff = 4 * lhi;
    int le = lane / 6;
    int s  = lane - le * 6;
    if (le > 9) { le = 9; s = 5; }                   // 4 dup lanes/wave (in-bounds)
    const int rb   = wid*64 + le*6;                  // element's slot base (in-wave)
    const int myk  = (tid >> 1) & 3;
    const int elem = blockIdx.x * ELB + wid*10 + le;
    const f32x4 zz = {0.f, 0.f, 0.f, 0.f};

    // tile-output row (act row) offset, shared by all MFMA sites
    int tOff[4];
    #pragma unroll
    for (int j = 0; j < 4; ++j) {
        int rowa = wid*64 + j*16 + llo;
        tOff[j] = rowa*16 + swg(rowa, lhi);
    }

    h2 X2[16];                                       // residual stream, packed f16 sigma pairs
    {
        const int ti  = (elem < nelem) ? (elem*SEQ + s) : 0;
        const int tok = toks[ti];
        #pragma unroll
        for (int g = 0; g < 4; ++g) {
            float4 alo = *(const float4*)&temb[tok*32 + 4*g];
            float4 ahi = *(const float4*)&temb[tok*32 + 16 + 4*g];
            float4 plo = *(const float4*)&pemb[s*32 + 4*g];
            float4 phi = *(const float4*)&pemb[s*32 + 16 + 4*g];
            X2[4*g+0] = __builtin_bit_cast(h2, pkh(alo.x + plo.x, ahi.x + phi.x));
            X2[4*g+1] = __builtin_bit_cast(h2, pkh(alo.y + plo.y, ahi.y + phi.y));
            X2[4*g+2] = __builtin_bit_cast(h2, pkh(alo.z + plo.z, ahi.z + phi.z));
            X2[4*g+3] = __builtin_bit_cast(h2, pkh(alo.w + plo.w, ahi.w + phi.w));
        }
    }

    #pragma unroll 1
    for (int L = 0; L < NL; ++L) {
        const unsigned int* wsL = ws + L * 6144;

        ln_write(X2, &S[XN], tid);                   // Xn (own slot)

        // ---- QKV: D = W_frag . Act_frag (swapped) -> one b128 write per tile ----
        uint4 q4[4];
        {
            h8 bq0 = ldh(wsL +          llo    *16 + boff);
            h8 bq1 = ldh(wsL +         (llo+16)*16 + boff);
            h8 bk0 = ldh(wsL +  512 +   llo    *16 + boff);
            h8 bk1 = ldh(wsL +  512 +  (llo+16)*16 + boff);
            h8 bv0 = ldh(wsL + 1024 +   llo    *16 + boff);
            h8 bv1 = ldh(wsL + 1024 +  (llo+16)*16 + boff);
            h8 aa[4];
            #pragma unroll
            for (int j = 0; j < 4; ++j) aa[j] = ldh(&S[XN + tOff[j]]);
            #pragma unroll
            for (int j = 0; j < 4; ++j) {            // K -> KP (b128)
                f32x4 k0 = __builtin_amdgcn_mfma_f32_16x16x32_f16(bk0, aa[j], zz, 0,0,0);
                f32x4 k1 = __builtin_amdgcn_mfma_f32_16x16x32_f16(bk1, aa[j], zz, 0,0,0);
                uint4 w;
                w.x = pkh(k0[0], k1[0]); w.y = pkh(k0[1], k1[1]);
                w.z = pkh(k0[2], k1[2]); w.w = pkh(k0[3], k1[3]);
                *(uint4*)&S[KP + tOff[j]] = w;
            }
            #pragma unroll
            for (int j = 0; j < 4; ++j) {            // Q -> XN (over Xn; aa read done)
                f32x4 qa = __builtin_amdgcn_mfma_f32_16x16x32_f16(bq0, aa[j], zz, 0,0,0);
                f32x4 qb = __builtin_amdgcn_mfma_f32_16x16x32_f16(bq1, aa[j], zz, 0,0,0);
                uint4 w;
                w.x = pkh(qa[0], qb[0]); w.y = pkh(qa[1], qb[1]);
                w.z = pkh(qa[2], qb[2]); w.w = pkh(qa[3], qb[3]);
                *(uint4*)&S[XN + tOff[j]] = w;
            }
            #pragma unroll
            for (int h = 0; h < 4; ++h)              // own-row Q (in-wave RAW, in-order DS)
                q4[h] = *(const uint4*)&S[XN + tid*16 + ((h ^ myk) << 2)];
            #pragma unroll
            for (int j = 0; j < 4; ++j) {            // V -> XN (over Q; q4 reads issued)
                f32x4 v0 = __builtin_amdgcn_mfma_f32_16x16x32_f16(bv0, aa[j], zz, 0,0,0);
                f32x4 v1 = __builtin_amdgcn_mfma_f32_16x16x32_f16(bv1, aa[j], zz, 0,0,0);
                uint4 w;
                w.x = pkh(v0[0], v1[0]); w.y = pkh(v0[1], v1[1]);
                w.z = pkh(v0[2], v1[2]); w.w = pkh(v0[3], v1[3]);
                *(uint4*)&S[XN + tOff[j]] = w;
            }
        }

        // ---- attention: ONLINE scores+PV in one pass ----
        // exp2 with folded scale: 0.35355339*log2(e) = 0.51006975. exp2(-1e30)=0 masks.
        {
            float den[4] = {0.f, 0.f, 0.f, 0.f};
            h2 O[16];
            #pragma unroll
            for (int w = 0; w < 16; ++w) O[w] = __builtin_bit_cast(h2, 0u);
            #pragma unroll
            for (int t = 0; t < SEQ; ++t) {
                int krow = rb + t;
                const unsigned int* kr = &S[KP + krow*16];
                const unsigned int* vr = &S[XN + krow*16];
                int kk4 = (krow >> 1) & 3;
                float msk = (t <= s) ? 0.f : -1e30f;
                #pragma unroll
                for (int h = 0; h < 4; ++h) {
                    uint4 kk = *(const uint4*)&kr[(h ^ kk4) << 2];
                    float d = dot2acc(q4[h].x, kk.x, 0.f);
                    d = dot2acc(q4[h].y, kk.y, d);
                    d = dot2acc(q4[h].z, kk.z, d);
                    d = dot2acc(q4[h].w, kk.w, d);
                    float e = exp2f(fmaf(d, 0.51006975f, msk));
                    den[h] += e;
                    h2 wg2 = __builtin_bit_cast(h2, pkh(e, e));
                    uint4 vv = *(const uint4*)&vr[(h ^ kk4) << 2];
                    O[4*h+0] += __builtin_bit_cast(h2, vv.x) * wg2;
                    O[4*h+1] += __builtin_bit_cast(h2, vv.y) * wg2;
                    O[4*h+2] += __builtin_bit_cast(h2, vv.z) * wg2;
                    O[4*h+3] += __builtin_bit_cast(h2, vv.w) * wg2;
                }
            }
            #pragma unroll
            for (int h = 0; h < 4; ++h) {            // normalize
                float rdh = __builtin_amdgcn_rcpf(den[h]);
                h2 rr = __builtin_bit_cast(h2, pkh(rdh, rdh));
                O[4*h+0] *= rr; O[4*h+1] *= rr; O[4*h+2] *= rr; O[4*h+3] *= rr;
            }
            #pragma unroll
            for (int g = 0; g < 4; ++g) {            // O -> KP own slot (over K; reads done)
                uint4 w;
                w.x = __builtin_bit_cast(unsigned int, O[4*g+0]);
                w.y = __builtin_bit_cast(unsigned int, O[4*g+1]);
                w.z = __builtin_bit_cast(unsigned int, O[4*g+2]);
                w.w = __builtin_bit_cast(unsigned int, O[4*g+3]);
                *(uint4*)&S[KP + tid*16 + ((g ^ myk) << 2)] = w;
            }
        }

        // ---- O.Wo (swapped): A=KP(O) frags -> D b128 into XN (over V) ----
        {
            h8 bo0 = ldh(wsL + 1536 +  llo    *16 + boff);
            h8 bo1 = ldh(wsL + 1536 + (llo+16)*16 + boff);
            #pragma unroll
            for (int j = 0; j < 4; ++j) {
                h8 a = ldh(&S[KP + tOff[j]]);
                f32x4 o0 = __builtin_amdgcn_mfma_f32_16x16x32_f16(bo0, a, zz, 0,0,0);
                f32x4 o1 = __builtin_amdgcn_mfma_f32_16x16x32_f16(bo1, a, zz, 0,0,0);
                uint4 w;
                w.x = pkh(o0[0], o1[0]); w.y = pkh(o0[1], o1[1]);
                w.z = pkh(o0[2], o1[2]); w.w = pkh(o0[3], o1[3]);
                *(uint4*)&S[XN + tOff[j]] = w;
            }
        }
        #pragma unroll
        for (int g = 0; g < 4; ++g) {                // residual (own slot, packed adds)
            uint4 v = *(const uint4*)&S[XN + tid*16 + ((g ^ myk) << 2)];
            X2[4*g+0] += __builtin_bit_cast(h2, v.x);
            X2[4*g+1] += __builtin_bit_cast(h2, v.y);
            X2[4*g+2] += __builtin_bit_cast(h2, v.z);
            X2[4*g+3] += __builtin_bit_cast(h2, v.w);
        }
        ln_write(X2, &S[KP], tid);                   // Xn2 -> KP (over O; A reads issued)

        // ---- FFN: Xn2 A-frags read once; H stays entirely in registers ----
        h8 aa2[4];
        #pragma unroll
        for (int j = 0; j < 4; ++j) aa2[j] = ldh(&S[KP + tOff[j]]);
        f32x4 cf[4][2];
        #pragma unroll
        for (int j = 0; j < 4; ++j) { cf[j][0] = zz; cf[j][1] = zz; }
        #pragma unroll
        for (int q = 0; q < 4; ++q) {
            const unsigned int* wq4 = wsL + 2048 + q*1024;
            h8 b10 = ldh(wq4 +        llo    *16 + boff);
            h8 b11 = ldh(wq4 +       (llo+16)*16 + boff);
            h8 b20 = ldh(wq4 + 512 +  llo    *16 + boff);
            h8 b21 = ldh(wq4 + 512 + (llo+16)*16 + boff);
            #pragma unroll
            for (int j = 0; j < 4; ++j) {
                f32x4 h0 = __builtin_amdgcn_mfma_f32_16x16x32_f16(b10, aa2[j], zz, 0,0,0);
                f32x4 h1 = __builtin_amdgcn_mfma_f32_16x16x32_f16(b11, aa2[j], zz, 0,0,0);
                uint4 w;
                w.x = gelu2(h0[0], h1[0]); w.y = gelu2(h0[1], h1[1]);
                w.z = gelu2(h0[2], h1[2]); w.w = gelu2(h0[3], h1[3]);
                h8 ah = __builtin_bit_cast(h8, w);   // fragment identity: no LDS
                cf[j][0] = __builtin_amdgcn_mfma_f32_16x16x32_f16(b20, ah, cf[j][0], 0,0,0);
                cf[j][1] = __builtin_amdgcn_mfma_f32_16x16x32_f16(b21, ah, cf[j][1], 0,0,0);
            }
        }
        #pragma unroll
        for (int j = 0; j < 4; ++j) {                // FFN2 out -> XN, b128
            uint4 w;
            w.x = pkh(cf[j][0][0], cf[j][1][0]); w.y = pkh(cf[j][0][1], cf[j][1][1]);
            w.z = pkh(cf[j][0][2], cf[j][1][2]); w.w = pkh(cf[j][0][3], cf[j][1][3]);
            *(uint4*)&S[XN + tOff[j]] = w;
        }
        #pragma unroll
        for (int g = 0; g < 4; ++g) {                // residual (own slot, packed adds)
            uint4 v = *(const uint4*)&S[XN + tid*16 + ((g ^ myk) << 2)];
            X2[4*g+0] += __builtin_bit_cast(h2, v.x);
            X2[4*g+1] += __builtin_bit_cast(h2, v.y);
            X2[4*g+2] += __builtin_bit_cast(h2, v.z);
            X2[4*g+3] += __builtin_bit_cast(h2, v.w);
        }
    }

    // ---- final LN + weight-tied logits (swapped; one b128 f32 write per j) ----
    ln_write(X2, &S[XN], tid);
    {
        h8 bt = ldh(ws + 12288 + llo*16 + boff);
        #pragma unroll
        for (int j = 0; j < 4; ++j) {
            h8 a = ldh(&S[XN + tOff[j]]);
            f32x4 lg = __builtin_amdgcn_mfma_f32_16x16x32_f16(bt, a, zz, 0,0,0);
            uint4 w;
            w.x = __float_as_uint(lg[0]); w.y = __float_as_uint(lg[1]);
            w.z = __float_as_uint(lg[2]); w.w = __float_as_uint(lg[3]);
            *(uint4*)&S[KP + tOff[j]] = w;           // word idx = vocab idx
        }
    }
    __syncthreads();                                 // the only barrier
    {
        const long long obase = (long long)blockIdx.x * (ELB*SEQ*VOC);   // 3600
        const long long tot   = (long long)nelem * (SEQ*VOC);
        // div-free epilogue: stride 256 = 17*15 + 1 over (rl, col) in base-15
        int rl  = tid / VOC;
        int col = tid - rl * VOC;
        for (int i = tid; i < ELB*SEQ*VOC; i += THREADS) {
            if (obase + i < tot) {
                int w    = rl / 60, r6 = rl - w*60;
                int slot = w*64 + r6;
                out[obase + i] = __uint_as_float(
                    S[KP + slot*16 + (((col >> 2) ^ ((slot >> 1) & 3)) << 2) + (col & 3)]);
            }
            col += 1; rl += 17;
            if (col >= VOC) { col -= VOC; rl += 1; }
        }
    }
}

extern "C" void kernel_launch(void* const* d_in, const int* in_sizes, int n_in,
                              void* d_out, int out_size, void* d_ws, size_t ws_size,
                              hipStream_t stream) {
    const int*   toks = (const int*)  d_in[0];
    const float* temb = (const float*)d_in[1];
    const float* pemb = (const float*)d_in[2];
    const float* wq   = (const float*)d_in[3];
    const float* wk   = (const float*)d_in[4];
    const float* wv   = (const float*)d_in[5];
    const float* wo   = (const float*)d_in[6];
    const float* w1   = (const float*)d_in[7];
    const float* w2   = (const float*)d_in[8];
    unsigned int* ws  = (unsigned int*)d_ws;         // 12544 u32 = 50 KB used
    float* out = (float*)d_out;
    const int nelem = in_sizes[0] / SEQ;             // 131072
    const int nblk  = (nelem + ELB - 1) / ELB;       // 3277

    prep<<<dim3(25), dim3(64), 0, stream>>>(temb, wq, wk, wv, wo, w1, w2, ws);
    tf_mfma<<<dim3(nblk), dim3(THREADS), 0, stream>>>(toks, temb, pemb, ws, out, nelem);
}